// Round 1
// 346.787 us; speedup vs baseline: 1.5139x; 1.5139x over previous
//
#include <hip/hip_runtime.h>
#include <hip/hip_bf16.h>

#define HW    5184
#define WIDTH 72
#define CIN   512
#define KC    256
#define VC    256
#define NS    110
#define BATCH 8

typedef unsigned short u16;
typedef unsigned int   u32;
typedef __attribute__((ext_vector_type(8))) short bf16x8;   // 8 bf16 = 4 VGPRs
typedef __attribute__((ext_vector_type(4))) float f32x4;

typedef const __attribute__((address_space(1))) u32* gp_t;
typedef __attribute__((address_space(3))) u32* lp_t;

__device__ __forceinline__ u32 f2bf1(float f) {
    u32 u = __float_as_uint(f);
    return (u + 0x7FFFu + ((u >> 16) & 1u)) >> 16;   // RNE
}
__device__ __forceinline__ u32 pack2(float a, float b) {
    return f2bf1(a) | (f2bf1(b) << 16);
}

// ---------------- prep: fold BN into per-channel scale/bias ----------------
__global__ void prep_kernel(const float* __restrict__ bk, const float* __restrict__ gamma,
                            const float* __restrict__ beta, const float* __restrict__ rmean,
                            const float* __restrict__ rvar, float* __restrict__ inv_out,
                            float* __restrict__ bc_out) {
    int i = threadIdx.x;  // 256 threads, one per Kc channel
    float inv = gamma[i] * rsqrtf(rvar[i] + 1e-5f);
    inv_out[i] = inv;
    bc_out[i]  = bk[i] * inv + beta[i] - rmean[i] * inv;
}

// ---------------- convert Wk [256][512] and Ww [512][256] fp32 -> bf16 ----------------
__global__ __launch_bounds__(256) void cvt_w_kernel(
    const float* __restrict__ Wk, const float* __restrict__ Ww,
    u16* __restrict__ Wkbf, u16* __restrict__ Wwbf)
{
    int j = (blockIdx.x * 256 + threadIdx.x) * 4;   // grid 256 -> 262144 elems
    const float* s; u16* d;
    if (j < KC * CIN) { s = Wk; d = Wkbf; }
    else { j -= KC * CIN; s = Ww; d = Wwbf; }
    float4 v = *(const float4*)&s[j];
    uint2 u;
    u.x = pack2(v.x, v.y);
    u.y = pack2(v.z, v.w);
    *(uint2*)&d[j] = u;
}

// ---------------- transpose+cvt: x [z][512][5184] f32 -> xT [z][5184][512] bf16 ----------------
__global__ __launch_bounds__(256) void transpose_cvt_kernel(
    const float* __restrict__ in, u16* __restrict__ out)
{
    const int z  = blockIdx.z;
    const int n0 = blockIdx.x * 32;   // HW
    const int k0 = blockIdx.y * 32;   // C
    __shared__ float t[32][33];
    const int tx = threadIdx.x & 31, ty = threadIdx.x >> 5;   // ty 0..7
    const float* src = in + ((size_t)z * CIN + k0) * HW + n0;
#pragma unroll
    for (int i = 0; i < 4; i++)
        t[ty + i * 8][tx] = src[(size_t)(ty + i * 8) * HW + tx];
    __syncthreads();
    u16* dst = out + ((size_t)z * HW + n0) * CIN + k0;
    const int kp  = (threadIdx.x & 15) * 2;
    const int nl0 = threadIdx.x >> 4;           // 0..15
#pragma unroll
    for (int j = 0; j < 2; j++) {
        int nl = nl0 + j * 16;
        u32 u = pack2(t[kp][nl], t[kp + 1][nl]);
        *(u32*)&dst[(size_t)nl * CIN + kp] = u;
    }
}

// ---------------- bf16 MFMA NT-GEMM: C[z][m][n] = sum_k A[m][k] * B[z][n][k] ----------------
// A bf16 [M][K], B bf16 [z][N][K], C fp32. 128x128 tile, BK=32, 4 waves (2x2, 64x64 each).
// LDS frag layout [kg][row][8]: global_load_lds dest = base + lane*16 (linear),
// ds_read_b128 frag reads fully coalesced, conflict-free. Epilogue: scale/bias (+relu).
__global__ __launch_bounds__(256) void gemm_nt_bf16(
    const u16* __restrict__ A, const u16* __restrict__ B, float* __restrict__ C,
    int M, int N, int K,
    const float* __restrict__ scale, const float* __restrict__ bias, int relu)
{
    const int n0 = blockIdx.x * 128;
    const int m0 = blockIdx.y * 128;
    const size_t boff = (size_t)blockIdx.z * N * K;
    const size_t coff = (size_t)blockIdx.z * M * N;
    const int tid  = threadIdx.x;
    const int wid  = tid >> 6;
    const int lane = tid & 63;

    __shared__ __align__(16) u16 As[4][128][8];   // 8 KB
    __shared__ __align__(16) u16 Bs[4][128][8];   // 8 KB

    // staging roles: wave w handles kg = {2*(w&1), 2*(w&1)+1}, row-half = (w>>1)*64
    const int kg0  = (wid & 1) * 2;
    const int half = (wid >> 1) * 64;

    const u16* gA = A + (size_t)(m0 + half + lane) * K + kg0 * 8;
    int nIdx = n0 + half + lane;
    if (nIdx > N - 1) nIdx = N - 1;               // clamp tail block (dup loads, stores masked)
    const u16* gB = B + boff + (size_t)nIdx * K + kg0 * 8;

    lp_t lA0 = (lp_t)&As[kg0][half][0];
    lp_t lA1 = (lp_t)&As[kg0 + 1][half][0];
    lp_t lB0 = (lp_t)&Bs[kg0][half][0];
    lp_t lB1 = (lp_t)&Bs[kg0 + 1][half][0];

    // compute roles: 2x2 waves, each owns 64x64
    const int wm  = (wid >> 1) * 64;
    const int wn  = (wid & 1) * 64;
    const int l16 = lane & 15;
    const int lq  = lane >> 4;                    // k-group 0..3

    f32x4 acc[4][4];
#pragma unroll
    for (int mi = 0; mi < 4; mi++)
#pragma unroll
        for (int ni = 0; ni < 4; ni++)
            acc[mi][ni] = (f32x4){0.f, 0.f, 0.f, 0.f};

    for (int k0 = 0; k0 < K; k0 += 32) {
        __builtin_amdgcn_global_load_lds((gp_t)(gA + k0),     lA0, 16, 0, 0);
        __builtin_amdgcn_global_load_lds((gp_t)(gA + k0 + 8), lA1, 16, 0, 0);
        __builtin_amdgcn_global_load_lds((gp_t)(gB + k0),     lB0, 16, 0, 0);
        __builtin_amdgcn_global_load_lds((gp_t)(gB + k0 + 8), lB1, 16, 0, 0);
        __syncthreads();   // compiler drains vmcnt(0) before barrier -> LDS tile ready

        bf16x8 af[4], bf[4];
#pragma unroll
        for (int i = 0; i < 4; i++) {
            af[i] = *(const bf16x8*)&As[lq][wm + i * 16 + l16][0];
            bf[i] = *(const bf16x8*)&Bs[lq][wn + i * 16 + l16][0];
        }
#pragma unroll
        for (int mi = 0; mi < 4; mi++)
#pragma unroll
            for (int ni = 0; ni < 4; ni++)
                acc[mi][ni] = __builtin_amdgcn_mfma_f32_16x16x32_bf16(
                    af[mi], bf[ni], acc[mi][ni], 0, 0, 0);
        __syncthreads();   // protect LDS before next-tile staging
    }

    // epilogue: D row = 4*lq + r, col = l16 (m89-verified layout)
#pragma unroll
    for (int mi = 0; mi < 4; mi++) {
        const int mb = m0 + wm + mi * 16 + lq * 4;
        float sc[4], bi[4];
#pragma unroll
        for (int r = 0; r < 4; r++) {
            sc[r] = scale ? scale[mb + r] : 1.0f;
            bi[r] = bias  ? bias[mb + r]  : 0.0f;
        }
#pragma unroll
        for (int ni = 0; ni < 4; ni++) {
            const int n = n0 + wn + ni * 16 + l16;
            if (n < N) {
#pragma unroll
                for (int r = 0; r < 4; r++) {
                    float v = acc[mi][ni][r] * sc[r] + bi[r];
                    if (relu) v = fmaxf(v, 0.f);
                    C[coff + (size_t)(mb + r) * N + n] = v;
                }
            }
        }
    }
}

// ---------------- PSP pooling: in [b][C][5184] -> out [b][110][C] ----------------
__global__ __launch_bounds__(128) void psp_pool_kernel(
    const float* __restrict__ in, float* __restrict__ out, int C)
{
    const int c = blockIdx.x;
    const int b = blockIdx.y;
    const int t = threadIdx.x;
    __shared__ float4 row4[1296];
    __shared__ float aux[100];
    float* row = (float*)row4;
    const float* src = in + ((size_t)b * C + c) * HW;
    for (int idx = t; idx < 1296; idx += 128)
        row4[idx] = *(const float4*)(src + idx * 4);
    __syncthreads();
    if (t < 64) {
        int r0 = (t >> 3) * 9, c0 = (t & 7) * 9;
        float s = 0.f;
        for (int i = 0; i < 9; i++)
            for (int j = 0; j < 9; j++) s += row[(r0 + i) * WIDTH + c0 + j];
        aux[t] = s;
    } else if (t < 100) {
        int tt = t - 64;
        int r0 = (tt / 6) * 12, c0 = (tt % 6) * 12;
        float s = 0.f;
        for (int i = 0; i < 12; i++)
            for (int j = 0; j < 12; j++) s += row[(r0 + i) * WIDTH + c0 + j];
        aux[64 + tt] = s;
    }
    __syncthreads();
    const size_t ob = ((size_t)b * NS) * C + c;
    if (t < 64) out[ob + (size_t)(46 + t) * C] = aux[t] * (1.f / 81.f);
    if (t < 36) out[ob + (size_t)(10 + t) * C] = aux[64 + t] * (1.f / 144.f);
    if (t < 9) {
        int r = t / 3, cc = t % 3;
        float s4 = aux[64 + (2 * r) * 6 + 2 * cc] + aux[64 + (2 * r) * 6 + 2 * cc + 1]
                 + aux[64 + (2 * r + 1) * 6 + 2 * cc] + aux[64 + (2 * r + 1) * 6 + 2 * cc + 1];
        out[ob + (size_t)(1 + t) * C] = s4 * (1.f / 576.f);
    }
    if (t == 0) {
        float s = 0.f;
        for (int i = 0; i < 64; i++) s += aux[i];
        out[ob] = s * (1.f / 5184.f);
    }
}

// ---------------- value: val[b][s][v] = sum_c Wv[v][c]*px[b][s][c] + bv[v] ----------------
__global__ __launch_bounds__(256) void value_kernel(
    const float* __restrict__ Wv, const float* __restrict__ bv,
    const float* __restrict__ px, float* __restrict__ val)
{
    const int s = blockIdx.x;
    const int b = blockIdx.y;
    const int v = threadIdx.x;
    __shared__ float pxl[CIN];
    const float* pxs = px + ((size_t)b * NS + s) * CIN;
    pxl[v] = pxs[v];
    pxl[v + 256] = pxs[v + 256];
    __syncthreads();
    float acc = bv[v];
    const float* wr = Wv + (size_t)v * CIN;
#pragma unroll 4
    for (int c4 = 0; c4 < 128; c4++) {
        const float4 w = *(const float4*)&wr[c4 * 4];
        acc += w.x * pxl[c4 * 4] + w.y * pxl[c4 * 4 + 1] + w.z * pxl[c4 * 4 + 2] + w.w * pxl[c4 * 4 + 3];
    }
    val[((size_t)b * NS + s) * VC + v] = acc;
}

// ---------------- fused attention: 32 pixels/block, 256 threads, LDS-staged K/V ----------------
// kq: [b][256][5184] f32, keyt: [b][110][256] f32, val: [b][110][256] f32
// ctx OUT: [b][5184][256] bf16 (TRANSPOSED, feeds NT-GEMM2 directly)
__global__ __launch_bounds__(256) void attn_kernel(
    const float* __restrict__ kq, const float* __restrict__ keyt,
    const float* __restrict__ val, u16* __restrict__ ctx)
{
    const int b = blockIdx.y;
    const int n0 = blockIdx.x * 32;
    const int tid = threadIdx.x;
    __shared__ float sim[32][113];                 // 14.4 KB, odd stride
    __shared__ __align__(16) float stage[6144];    // 24 KB union: key dbuf / val dbuf

    const float* keyb = keyt + (size_t)b * NS * KC;
    const float* valb = val + (size_t)b * NS * VC;

    // ==== phase 1: sim = q . keyt, keyt staged per 16-channel chunk ====
    {
        const int px = tid & 31;
        const int sg = tid >> 5;
        const float* kb = kq + (size_t)b * KC * HW + n0 + px;
        float acc[14];
#pragma unroll
        for (int j = 0; j < 14; j++) acc[j] = 0.f;

        const int i0 = tid;           // < 440 always
        const int i1 = tid + 256;     // guard < 440
        {   // prologue: chunk 0
            float4 a = *(const float4*)&keyb[(i0 >> 2) * KC + (i0 & 3) * 4];
            *(float4*)&stage[(i0 >> 2) * 16 + (i0 & 3) * 4] = a;
            if (i1 < 440) {
                float4 c = *(const float4*)&keyb[(i1 >> 2) * KC + (i1 & 3) * 4];
                *(float4*)&stage[(i1 >> 2) * 16 + (i1 & 3) * 4] = c;
            }
        }
        __syncthreads();

        for (int ch = 0; ch < 16; ++ch) {
            const int buf = ch & 1;
            float4 sa = make_float4(0.f, 0.f, 0.f, 0.f);
            float4 sb = make_float4(0.f, 0.f, 0.f, 0.f);
            if (ch < 15) {
                const int c0n = (ch + 1) * 16;
                sa = *(const float4*)&keyb[(i0 >> 2) * KC + c0n + (i0 & 3) * 4];
                if (i1 < 440)
                    sb = *(const float4*)&keyb[(i1 >> 2) * KC + c0n + (i1 & 3) * 4];
            }
            float q[16];
#pragma unroll
            for (int i = 0; i < 16; i++) q[i] = kb[(size_t)(ch * 16 + i) * HW];
            const float* kbuf = &stage[buf * 1792];
#pragma unroll
            for (int j = 0; j < 14; j++) {
                const int s = sg + 8 * j;
                if (j < 13 || sg < 6) {   // s < NS
#pragma unroll
                    for (int c4 = 0; c4 < 4; c4++) {
                        const float4 kv = *(const float4*)&kbuf[s * 16 + c4 * 4];
                        acc[j] += q[c4 * 4 + 0] * kv.x + q[c4 * 4 + 1] * kv.y
                                + q[c4 * 4 + 2] * kv.z + q[c4 * 4 + 3] * kv.w;
                    }
                }
            }
            if (ch < 15) {
                float* kw = &stage[(buf ^ 1) * 1792];
                *(float4*)&kw[(i0 >> 2) * 16 + (i0 & 3) * 4] = sa;
                if (i1 < 440)
                    *(float4*)&kw[(i1 >> 2) * 16 + (i1 & 3) * 4] = sb;
            }
            __syncthreads();
        }
#pragma unroll
        for (int j = 0; j < 14; j++) {
            const int s = sg + 8 * j;
            if (s < NS) sim[px][s] = acc[j] * 0.0625f;  // * Kc^-0.5
        }
    }
    __syncthreads();

    // ==== phase 2: softmax; 8 lanes per pixel row ====
    {
        const int p = tid >> 3;
        const int part = tid & 7;
        float m = -1e30f;
        for (int s = part; s < NS; s += 8) m = fmaxf(m, sim[p][s]);
        m = fmaxf(m, __shfl_xor(m, 1));
        m = fmaxf(m, __shfl_xor(m, 2));
        m = fmaxf(m, __shfl_xor(m, 4));
        float sum = 0.f;
        for (int s = part; s < NS; s += 8) { float e = __expf(sim[p][s] - m); sim[p][s] = e; sum += e; }
        sum += __shfl_xor(sum, 1);
        sum += __shfl_xor(sum, 2);
        sum += __shfl_xor(sum, 4);
        const float rn = 1.f / sum;
        for (int s = part; s < NS; s += 8) sim[p][s] *= rn;
    }
    __syncthreads();

    // ==== phase 3: ctx = sim . val, val staged per 12-s chunk ====
    {
        const int px = tid & 31;
        const int vg = tid >> 5;
        const int v0 = vg * 32;
        float acc2[32];
#pragma unroll
        for (int v = 0; v < 32; v++) acc2[v] = 0.f;

        {   // prologue: chunk 0 (s = 0..11, all < NS)
            float4 a = *(const float4*)&valb[(tid >> 6) * VC + (tid & 63) * 4];
            *(float4*)&stage[(tid >> 6) * 256 + (tid & 63) * 4] = a;
            const int iA = tid + 256;
            float4 c = *(const float4*)&valb[(iA >> 6) * VC + (iA & 63) * 4];
            *(float4*)&stage[(iA >> 6) * 256 + (iA & 63) * 4] = c;
            const int iB = tid + 512;
            float4 d = *(const float4*)&valb[(iB >> 6) * VC + (iB & 63) * 4];
            *(float4*)&stage[(iB >> 6) * 256 + (iB & 63) * 4] = d;
        }
        __syncthreads();

        const int NCH = (NS + 11) / 12;  // 10
        for (int c = 0; c < NCH; ++c) {
            const int buf = c & 1;
            const int s0 = c * 12;
            float4 va = make_float4(0.f, 0.f, 0.f, 0.f);
            float4 vb = make_float4(0.f, 0.f, 0.f, 0.f);
            float4 vc = make_float4(0.f, 0.f, 0.f, 0.f);
            if (c + 1 < NCH) {
                const int s0n = s0 + 12;
                const int iA = tid, iB = tid + 256, iC = tid + 512;
                if (s0n + (iA >> 6) < NS) va = *(const float4*)&valb[(s0n + (iA >> 6)) * VC + (iA & 63) * 4];
                if (s0n + (iB >> 6) < NS) vb = *(const float4*)&valb[(s0n + (iB >> 6)) * VC + (iB & 63) * 4];
                if (s0n + (iC >> 6) < NS) vc = *(const float4*)&valb[(s0n + (iC >> 6)) * VC + (iC & 63) * 4];
            }
            const int len = (NS - s0) < 12 ? (NS - s0) : 12;
            const float* vbuf = &stage[buf * 3072];
            for (int i = 0; i < len; ++i) {
                const float sp = sim[px][s0 + i];
#pragma unroll
                for (int v4 = 0; v4 < 8; v4++) {
                    const float4 vv = *(const float4*)&vbuf[i * 256 + v0 + v4 * 4];
                    acc2[v4 * 4 + 0] += sp * vv.x;
                    acc2[v4 * 4 + 1] += sp * vv.y;
                    acc2[v4 * 4 + 2] += sp * vv.z;
                    acc2[v4 * 4 + 3] += sp * vv.w;
                }
            }
            if (c + 1 < NCH) {
                float* vw = &stage[(buf ^ 1) * 3072];
                *(float4*)&vw[(tid >> 6) * 256 + (tid & 63) * 4] = va;
                const int iB = tid + 256, iC = tid + 512;
                *(float4*)&vw[(iB >> 6) * 256 + (iB & 63) * 4] = vb;
                *(float4*)&vw[(iC >> 6) * 256 + (iC & 63) * 4] = vc;
            }
            __syncthreads();
        }

        // transposed bf16 write: ctx[b][n0+px][v0..v0+31]
        u16* cb = ctx + ((size_t)b * HW + n0 + px) * VC + v0;
#pragma unroll
        for (int g = 0; g < 4; g++) {
            uint4 u;
            u.x = pack2(acc2[g * 8 + 0], acc2[g * 8 + 1]);
            u.y = pack2(acc2[g * 8 + 2], acc2[g * 8 + 3]);
            u.z = pack2(acc2[g * 8 + 4], acc2[g * 8 + 5]);
            u.w = pack2(acc2[g * 8 + 6], acc2[g * 8 + 7]);
            *(uint4*)&cb[g * 8] = u;
        }
    }
}

extern "C" void kernel_launch(void* const* d_in, const int* in_sizes, int n_in,
                              void* d_out, int out_size, void* d_ws, size_t ws_size,
                              hipStream_t stream)
{
    const float* x     = (const float*)d_in[0];
    const float* Wk    = (const float*)d_in[1];
    const float* bk    = (const float*)d_in[2];
    const float* gamma = (const float*)d_in[3];
    const float* beta  = (const float*)d_in[4];
    const float* rmean = (const float*)d_in[5];
    const float* rvar  = (const float*)d_in[6];
    const float* Wv    = (const float*)d_in[7];
    const float* bv    = (const float*)d_in[8];
    const float* Ww    = (const float*)d_in[9];
    const float* bw    = (const float*)d_in[10];
    float* out = (float*)d_out;

    float* ws    = (float*)d_ws;
    float* k_ws  = ws;                                        // [8][256][5184] f32
    u16*   xT    = (u16*)(k_ws + (size_t)BATCH * KC * HW);    // [8][5184][512] bf16
    u16*   ctxT  = xT;                                        // alias: [8][5184][256] bf16 (xT dead after gemm1)
    float* px    = (float*)(xT + (size_t)BATCH * HW * CIN);   // [8][110][512]
    float* keytT = px    + (size_t)BATCH * NS * CIN;          // [8][110][256]
    float* val   = keytT + (size_t)BATCH * NS * KC;           // [8][110][256]
    u16*   Wkbf  = (u16*)(val + (size_t)BATCH * NS * VC);     // [256][512] bf16
    u16*   Wwbf  = Wkbf + (size_t)KC * CIN;                   // [512][256] bf16
    float* inv   = (float*)(Wwbf + (size_t)CIN * VC);         // [256]
    float* bc    = inv + 256;                                 // [256]

    prep_kernel<<<1, 256, 0, stream>>>(bk, gamma, beta, rmean, rvar, inv, bc);
    cvt_w_kernel<<<256, 256, 0, stream>>>(Wk, Ww, Wkbf, Wwbf);
    psp_pool_kernel<<<dim3(CIN, BATCH), 128, 0, stream>>>(x, px, CIN);
    transpose_cvt_kernel<<<dim3(HW / 32, CIN / 32, BATCH), 256, 0, stream>>>(x, xT);
    // k = relu(BN(Wk @ x)) : M=256, N=5184, K=512
    gemm_nt_bf16<<<dim3((HW + 127) / 128, KC / 128, BATCH), 256, 0, stream>>>(
        Wkbf, xT, k_ws, KC, HW, CIN, inv, bc, 1);
    psp_pool_kernel<<<dim3(KC, BATCH), 128, 0, stream>>>(k_ws, keytT, KC);
    value_kernel<<<dim3(NS, BATCH), 256, 0, stream>>>(Wv, bv, px, val);
    attn_kernel<<<dim3(HW / 32, BATCH), 256, 0, stream>>>(k_ws, keytT, val, ctxT);
    // out = Ww @ ctx + bw : M=512, N=5184, K=256
    gemm_nt_bf16<<<dim3((HW + 127) / 128, CIN / 128, BATCH), 256, 0, stream>>>(
        Wwbf, ctxT, out, CIN, HW, VC, nullptr, bw, 0);
}

// Round 2
// 265.392 us; speedup vs baseline: 1.9782x; 1.3067x over previous
//
#include <hip/hip_runtime.h>
#include <hip/hip_bf16.h>

#define HW    5184
#define WIDTH 72
#define CIN   512
#define KC    256
#define VC    256
#define NS    110
#define NSP   112   // padded s for QK^T (7*16)
#define SPV   128   // padded s for PV k-dim (4*32)
#define BATCH 8

typedef unsigned short u16;
typedef unsigned int   u32;
typedef __attribute__((ext_vector_type(8))) short bf16x8;   // 8 bf16 = 4 VGPRs
typedef __attribute__((ext_vector_type(4))) float f32x4;

typedef const __attribute__((address_space(1))) u32* gp_t;
typedef __attribute__((address_space(3))) u32* lp_t;

__device__ __forceinline__ u32 f2bf1(float f) {
    u32 u = __float_as_uint(f);
    return (u + 0x7FFFu + ((u >> 16) & 1u)) >> 16;   // RNE
}
__device__ __forceinline__ u32 pack2(float a, float b) {
    return f2bf1(a) | (f2bf1(b) << 16);
}

// ---------------- prep: fold BN into per-channel scale/bias ----------------
__global__ void prep_kernel(const float* __restrict__ bk, const float* __restrict__ gamma,
                            const float* __restrict__ beta, const float* __restrict__ rmean,
                            const float* __restrict__ rvar, float* __restrict__ inv_out,
                            float* __restrict__ bc_out) {
    int i = threadIdx.x;  // 256 threads, one per Kc channel
    float inv = gamma[i] * rsqrtf(rvar[i] + 1e-5f);
    inv_out[i] = inv;
    bc_out[i]  = bk[i] * inv + beta[i] - rmean[i] * inv;
}

// ---------------- convert Wk [256][512] and Ww [512][256] fp32 -> bf16 ----------------
__global__ __launch_bounds__(256) void cvt_w_kernel(
    const float* __restrict__ Wk, const float* __restrict__ Ww,
    u16* __restrict__ Wkbf, u16* __restrict__ Wwbf)
{
    int j = (blockIdx.x * 256 + threadIdx.x) * 4;   // grid 256 -> 262144 elems
    const float* s; u16* d;
    if (j < KC * CIN) { s = Wk; d = Wkbf; }
    else { j -= KC * CIN; s = Ww; d = Wwbf; }
    float4 v = *(const float4*)&s[j];
    uint2 u;
    u.x = pack2(v.x, v.y);
    u.y = pack2(v.z, v.w);
    *(uint2*)&d[j] = u;
}

// ---------------- transpose+cvt: in [z][C][5184] f32 -> out [z][5184][C] bf16 ----------------
__global__ __launch_bounds__(256) void transpose_cvt_kernel(
    const float* __restrict__ in, u16* __restrict__ out, int C)
{
    const int z  = blockIdx.z;
    const int n0 = blockIdx.x * 32;   // HW
    const int k0 = blockIdx.y * 32;   // C
    __shared__ float t[32][33];
    const int tx = threadIdx.x & 31, ty = threadIdx.x >> 5;   // ty 0..7
    const float* src = in + ((size_t)z * C + k0) * HW + n0;
#pragma unroll
    for (int i = 0; i < 4; i++)
        t[ty + i * 8][tx] = src[(size_t)(ty + i * 8) * HW + tx];
    __syncthreads();
    u16* dst = out + ((size_t)z * HW + n0) * C + k0;
    const int kp  = (threadIdx.x & 15) * 2;
    const int nl0 = threadIdx.x >> 4;           // 0..15
#pragma unroll
    for (int j = 0; j < 2; j++) {
        int nl = nl0 + j * 16;
        u32 u = pack2(t[kp][nl], t[kp + 1][nl]);
        *(u32*)&dst[(size_t)nl * C + kp] = u;
    }
}

// ---------------- bf16 MFMA NT-GEMM: C[z][m][n] = sum_k A[m][k] * B[z][n][k] ----------------
__global__ __launch_bounds__(256) void gemm_nt_bf16(
    const u16* __restrict__ A, const u16* __restrict__ B, float* __restrict__ C,
    int M, int N, int K,
    const float* __restrict__ scale, const float* __restrict__ bias, int relu)
{
    const int n0 = blockIdx.x * 128;
    const int m0 = blockIdx.y * 128;
    const size_t boff = (size_t)blockIdx.z * N * K;
    const size_t coff = (size_t)blockIdx.z * M * N;
    const int tid  = threadIdx.x;
    const int wid  = tid >> 6;
    const int lane = tid & 63;

    __shared__ __align__(16) u16 As[4][128][8];   // 8 KB
    __shared__ __align__(16) u16 Bs[4][128][8];   // 8 KB

    const int kg0  = (wid & 1) * 2;
    const int half = (wid >> 1) * 64;

    const u16* gA = A + (size_t)(m0 + half + lane) * K + kg0 * 8;
    int nIdx = n0 + half + lane;
    if (nIdx > N - 1) nIdx = N - 1;               // clamp tail block (dup loads, stores masked)
    const u16* gB = B + boff + (size_t)nIdx * K + kg0 * 8;

    lp_t lA0 = (lp_t)&As[kg0][half][0];
    lp_t lA1 = (lp_t)&As[kg0 + 1][half][0];
    lp_t lB0 = (lp_t)&Bs[kg0][half][0];
    lp_t lB1 = (lp_t)&Bs[kg0 + 1][half][0];

    const int wm  = (wid >> 1) * 64;
    const int wn  = (wid & 1) * 64;
    const int l16 = lane & 15;
    const int lq  = lane >> 4;

    f32x4 acc[4][4];
#pragma unroll
    for (int mi = 0; mi < 4; mi++)
#pragma unroll
        for (int ni = 0; ni < 4; ni++)
            acc[mi][ni] = (f32x4){0.f, 0.f, 0.f, 0.f};

    for (int k0 = 0; k0 < K; k0 += 32) {
        __builtin_amdgcn_global_load_lds((gp_t)(gA + k0),     lA0, 16, 0, 0);
        __builtin_amdgcn_global_load_lds((gp_t)(gA + k0 + 8), lA1, 16, 0, 0);
        __builtin_amdgcn_global_load_lds((gp_t)(gB + k0),     lB0, 16, 0, 0);
        __builtin_amdgcn_global_load_lds((gp_t)(gB + k0 + 8), lB1, 16, 0, 0);
        __syncthreads();

        bf16x8 af[4], bf[4];
#pragma unroll
        for (int i = 0; i < 4; i++) {
            af[i] = *(const bf16x8*)&As[lq][wm + i * 16 + l16][0];
            bf[i] = *(const bf16x8*)&Bs[lq][wn + i * 16 + l16][0];
        }
#pragma unroll
        for (int mi = 0; mi < 4; mi++)
#pragma unroll
            for (int ni = 0; ni < 4; ni++)
                acc[mi][ni] = __builtin_amdgcn_mfma_f32_16x16x32_bf16(
                    af[mi], bf[ni], acc[mi][ni], 0, 0, 0);
        __syncthreads();
    }

#pragma unroll
    for (int mi = 0; mi < 4; mi++) {
        const int mb = m0 + wm + mi * 16 + lq * 4;
        float sc[4], bi[4];
#pragma unroll
        for (int r = 0; r < 4; r++) {
            sc[r] = scale ? scale[mb + r] : 1.0f;
            bi[r] = bias  ? bias[mb + r]  : 0.0f;
        }
#pragma unroll
        for (int ni = 0; ni < 4; ni++) {
            const int n = n0 + wn + ni * 16 + l16;
            if (n < N) {
#pragma unroll
                for (int r = 0; r < 4; r++) {
                    float v = acc[mi][ni][r] * sc[r] + bi[r];
                    if (relu) v = fmaxf(v, 0.f);
                    C[coff + (size_t)(mb + r) * N + n] = v;
                }
            }
        }
    }
}

// ---------------- PSP pooling fp32: in [b][C][5184] -> out [b][110][C] ----------------
__global__ __launch_bounds__(128) void psp_pool_kernel(
    const float* __restrict__ in, float* __restrict__ out, int C)
{
    const int c = blockIdx.x;
    const int b = blockIdx.y;
    const int t = threadIdx.x;
    __shared__ float4 row4[1296];
    __shared__ float aux[100];
    float* row = (float*)row4;
    const float* src = in + ((size_t)b * C + c) * HW;
    for (int idx = t; idx < 1296; idx += 128)
        row4[idx] = *(const float4*)(src + idx * 4);
    __syncthreads();
    if (t < 64) {
        int r0 = (t >> 3) * 9, c0 = (t & 7) * 9;
        float s = 0.f;
        for (int i = 0; i < 9; i++)
            for (int j = 0; j < 9; j++) s += row[(r0 + i) * WIDTH + c0 + j];
        aux[t] = s;
    } else if (t < 100) {
        int tt = t - 64;
        int r0 = (tt / 6) * 12, c0 = (tt % 6) * 12;
        float s = 0.f;
        for (int i = 0; i < 12; i++)
            for (int j = 0; j < 12; j++) s += row[(r0 + i) * WIDTH + c0 + j];
        aux[64 + tt] = s;
    }
    __syncthreads();
    const size_t ob = ((size_t)b * NS) * C + c;
    if (t < 64) out[ob + (size_t)(46 + t) * C] = aux[t] * (1.f / 81.f);
    if (t < 36) out[ob + (size_t)(10 + t) * C] = aux[64 + t] * (1.f / 144.f);
    if (t < 9) {
        int r = t / 3, cc = t % 3;
        float s4 = aux[64 + (2 * r) * 6 + 2 * cc] + aux[64 + (2 * r) * 6 + 2 * cc + 1]
                 + aux[64 + (2 * r + 1) * 6 + 2 * cc] + aux[64 + (2 * r + 1) * 6 + 2 * cc + 1];
        out[ob + (size_t)(1 + t) * C] = s4 * (1.f / 576.f);
    }
    if (t == 0) {
        float s = 0.f;
        for (int i = 0; i < 64; i++) s += aux[i];
        out[ob] = s * (1.f / 5184.f);
    }
}

// ---------------- PSP pooling bf16: in [b][256][5184] -> out [b][112][256] bf16 ----------------
__global__ __launch_bounds__(128) void psp_pool_bf16_kernel(
    const float* __restrict__ in, u16* __restrict__ out)
{
    const int c = blockIdx.x;   // 0..255
    const int b = blockIdx.y;
    const int t = threadIdx.x;
    __shared__ float4 row4[1296];
    __shared__ float aux[100];
    float* row = (float*)row4;
    const float* src = in + ((size_t)b * KC + c) * HW;
    for (int idx = t; idx < 1296; idx += 128)
        row4[idx] = *(const float4*)(src + idx * 4);
    __syncthreads();
    if (t < 64) {
        int r0 = (t >> 3) * 9, c0 = (t & 7) * 9;
        float s = 0.f;
        for (int i = 0; i < 9; i++)
            for (int j = 0; j < 9; j++) s += row[(r0 + i) * WIDTH + c0 + j];
        aux[t] = s;
    } else if (t < 100) {
        int tt = t - 64;
        int r0 = (tt / 6) * 12, c0 = (tt % 6) * 12;
        float s = 0.f;
        for (int i = 0; i < 12; i++)
            for (int j = 0; j < 12; j++) s += row[(r0 + i) * WIDTH + c0 + j];
        aux[64 + tt] = s;
    }
    __syncthreads();
    u16* ob = out + (size_t)b * NSP * KC + c;
    if (t < 64) ob[(size_t)(46 + t) * KC] = (u16)f2bf1(aux[t] * (1.f / 81.f));
    if (t < 36) ob[(size_t)(10 + t) * KC] = (u16)f2bf1(aux[64 + t] * (1.f / 144.f));
    if (t < 9) {
        int r = t / 3, cc = t % 3;
        float s4 = aux[64 + (2 * r) * 6 + 2 * cc] + aux[64 + (2 * r) * 6 + 2 * cc + 1]
                 + aux[64 + (2 * r + 1) * 6 + 2 * cc] + aux[64 + (2 * r + 1) * 6 + 2 * cc + 1];
        ob[(size_t)(1 + t) * KC] = (u16)f2bf1(s4 * (1.f / 576.f));
    }
    if (t == 0) {
        float s = 0.f;
        for (int i = 0; i < 64; i++) s += aux[i];
        ob[0] = (u16)f2bf1(s * (1.f / 5184.f));
        ob[(size_t)110 * KC] = 0;   // zero pad rows (NaN safety)
        ob[(size_t)111 * KC] = 0;
    }
}

// ---------------- value: valT[b][v][s] = bf16(sum_c Wv[v][c]*px[b][s][c] + bv[v]) ----------------
__global__ __launch_bounds__(256) void value_kernel(
    const float* __restrict__ Wv, const float* __restrict__ bv,
    const float* __restrict__ px, u16* __restrict__ valT)
{
    const int s = blockIdx.x;   // 0..127 (>=110 writes zero pad)
    const int b = blockIdx.y;
    const int v = threadIdx.x;
    if (s >= NS) { valT[((size_t)b * VC + v) * SPV + s] = 0; return; }
    __shared__ float pxl[CIN];
    const float* pxs = px + ((size_t)b * NS + s) * CIN;
    pxl[v] = pxs[v];
    pxl[v + 256] = pxs[v + 256];
    __syncthreads();
    float acc = bv[v];
    const float* wr = Wv + (size_t)v * CIN;
#pragma unroll 4
    for (int c4 = 0; c4 < 128; c4++) {
        const float4 w = *(const float4*)&wr[c4 * 4];
        acc += w.x * pxl[c4 * 4] + w.y * pxl[c4 * 4 + 1] + w.z * pxl[c4 * 4 + 2] + w.w * pxl[c4 * 4 + 3];
    }
    valT[((size_t)b * VC + v) * SPV + s] = (u16)f2bf1(acc);
}

// ---------------- MFMA attention: 64 px/block, 4 waves x 16 px ----------------
// qT: [b][5184][256] bf16, keyt: [b][112][256] bf16, valT: [b][256][128] bf16
// ctxT out: [b][5184][256] bf16
__global__ __launch_bounds__(256) void attn_mfma_kernel(
    const u16* __restrict__ qT, const u16* __restrict__ keyt,
    const u16* __restrict__ valT, u16* __restrict__ ctxT)
{
    const int b    = blockIdx.y;
    const int tid  = threadIdx.x;
    const int wid  = tid >> 6;
    const int lane = tid & 63;
    const int l16  = lane & 15;
    const int lq   = lane >> 4;
    const int px0  = blockIdx.x * 64 + wid * 16;   // wave's 16-px row base

    __shared__ __align__(16) u16 P[64 * 128];      // XOR-swizzled [row][s] bf16, 16 KB
    char* Pb = (char*)P;

    // zero P (covers s>=112 pad; swizzle is a within-row permutation so linear zero is fine)
    {
        u32* p32 = (u32*)P;
#pragma unroll
        for (int i = 0; i < 16; i++) p32[tid + i * 256] = 0;
    }

    // ==== QK^T: acc[ni] is the 16x16 D tile (rows px 4*lq+r, cols s ni*16+l16) ====
    const u16* qrow = qT + ((size_t)b * HW + px0 + l16) * KC + lq * 8;
    const u16* krow = keyt + (size_t)b * NSP * KC + lq * 8;
    f32x4 acc[7];
#pragma unroll
    for (int ni = 0; ni < 7; ni++) acc[ni] = (f32x4){0.f, 0.f, 0.f, 0.f};
#pragma unroll
    for (int ks = 0; ks < 8; ks++) {
        bf16x8 aq = *(const bf16x8*)(qrow + ks * 32);
#pragma unroll
        for (int ni = 0; ni < 7; ni++) {
            bf16x8 bk = *(const bf16x8*)(krow + (size_t)(ni * 16 + l16) * KC + ks * 32);
            acc[ni] = __builtin_amdgcn_mfma_f32_16x16x32_bf16(aq, bk, acc[ni], 0, 0, 0);
        }
    }

    // mask pad columns s=110,111 (ni=6, l16>=14)
    if (l16 >= 14) acc[6] = (f32x4){-1e30f, -1e30f, -1e30f, -1e30f};

    // ==== softmax over s (in-register; row r's s-values live across 16 lanes x 7 regs) ====
    float mx[4], sm[4], rn[4];
#pragma unroll
    for (int r = 0; r < 4; r++) {
        float m = acc[0][r];
#pragma unroll
        for (int ni = 1; ni < 7; ni++) m = fmaxf(m, acc[ni][r]);
        m = fmaxf(m, __shfl_xor(m, 1));
        m = fmaxf(m, __shfl_xor(m, 2));
        m = fmaxf(m, __shfl_xor(m, 4));
        m = fmaxf(m, __shfl_xor(m, 8));
        mx[r] = m * 0.0625f;     // fold Kc^-0.5
        sm[r] = 0.f;
    }

    __syncthreads();   // P zero done (cross-wave) before P writes

    const int prow = wid * 16 + 4 * lq;
#pragma unroll
    for (int ni = 0; ni < 7; ni++) {
#pragma unroll
        for (int r = 0; r < 4; r++) {
            float p = __expf(acc[ni][r] * 0.0625f - mx[r]);   // masked cols -> exp(-huge)=0
            sm[r] += p;
            const int row = prow + r;
            int byte = row * 256 + (ni * 16 + l16) * 2;
            byte ^= (row & 7) << 4;
            *(u16*)(Pb + byte) = (u16)f2bf1(p);
        }
    }
#pragma unroll
    for (int r = 0; r < 4; r++) {
        float s = sm[r];
        s += __shfl_xor(s, 1);
        s += __shfl_xor(s, 2);
        s += __shfl_xor(s, 4);
        s += __shfl_xor(s, 8);
        rn[r] = 1.f / s;
    }

    __syncthreads();   // P writes visible (wave-private rows, but cheap + safe)

    // ==== PV: ctx[px][v] = sum_s P[px][s] * valT[v][s] ====
    f32x4 acc2[16];
#pragma unroll
    for (int ni = 0; ni < 16; ni++) acc2[ni] = (f32x4){0.f, 0.f, 0.f, 0.f};
    const u16* vrow = valT + ((size_t)b * VC + l16) * SPV + lq * 8;
    const int arow = wid * 16 + l16;
    const int aswz = (arow & 7) << 4;
#pragma unroll
    for (int ks = 0; ks < 4; ks++) {
        int byte = arow * 256 + ks * 64 + lq * 16;
        byte ^= aswz;
        bf16x8 pa = *(const bf16x8*)(Pb + byte);
#pragma unroll
        for (int ni = 0; ni < 16; ni++) {
            bf16x8 bv = *(const bf16x8*)(vrow + (size_t)ni * 16 * SPV + ks * 32);
            acc2[ni] = __builtin_amdgcn_mfma_f32_16x16x32_bf16(pa, bv, acc2[ni], 0, 0, 0);
        }
    }

    // epilogue: normalize by row sum, write ctxT[b][px][v] bf16
    u16* crow = ctxT + ((size_t)b * HW + px0 + 4 * lq) * VC + l16;
#pragma unroll
    for (int ni = 0; ni < 16; ni++) {
#pragma unroll
        for (int r = 0; r < 4; r++) {
            float v = acc2[ni][r] * rn[r];
            crow[(size_t)r * VC + ni * 16] = (u16)f2bf1(v);
        }
    }
}

extern "C" void kernel_launch(void* const* d_in, const int* in_sizes, int n_in,
                              void* d_out, int out_size, void* d_ws, size_t ws_size,
                              hipStream_t stream)
{
    const float* x     = (const float*)d_in[0];
    const float* Wk    = (const float*)d_in[1];
    const float* bk    = (const float*)d_in[2];
    const float* gamma = (const float*)d_in[3];
    const float* beta  = (const float*)d_in[4];
    const float* rmean = (const float*)d_in[5];
    const float* rvar  = (const float*)d_in[6];
    const float* Wv    = (const float*)d_in[7];
    const float* bv    = (const float*)d_in[8];
    const float* Ww    = (const float*)d_in[9];
    const float* bw    = (const float*)d_in[10];
    float* out = (float*)d_out;

    float* ws    = (float*)d_ws;
    float* k_ws  = ws;                                        // [8][256][5184] f32
    u16*   xT    = (u16*)(k_ws + (size_t)BATCH * KC * HW);    // [8][5184][512] bf16
    u16*   kT    = xT;                                        // alias (xT dead after gemm1): [8][5184][256]
    u16*   ctxT  = xT + (size_t)BATCH * HW * KC;              // alias second half: [8][5184][256]
    float* px    = (float*)(xT + (size_t)BATCH * HW * CIN);   // [8][110][512] f32
    u16*   keytb = (u16*)(px + (size_t)BATCH * NS * CIN);     // [8][112][256] bf16
    u16*   valT  = keytb + (size_t)BATCH * NSP * KC;          // [8][256][128] bf16
    u16*   Wkbf  = valT + (size_t)BATCH * VC * SPV;           // [256][512] bf16
    u16*   Wwbf  = Wkbf + (size_t)KC * CIN;                   // [512][256] bf16
    float* inv   = (float*)(Wwbf + (size_t)CIN * VC);         // [256]
    float* bc    = inv + 256;                                 // [256]

    prep_kernel<<<1, 256, 0, stream>>>(bk, gamma, beta, rmean, rvar, inv, bc);
    cvt_w_kernel<<<256, 256, 0, stream>>>(Wk, Ww, Wkbf, Wwbf);
    psp_pool_kernel<<<dim3(CIN, BATCH), 128, 0, stream>>>(x, px, CIN);
    transpose_cvt_kernel<<<dim3(HW / 32, CIN / 32, BATCH), 256, 0, stream>>>(x, xT, CIN);
    // k = relu(BN(Wk @ x)) : M=256, N=5184, K=512
    gemm_nt_bf16<<<dim3((HW + 127) / 128, KC / 128, BATCH), 256, 0, stream>>>(
        Wkbf, xT, k_ws, KC, HW, CIN, inv, bc, 1);
    // kT (= qT) bf16 for attention A operand
    transpose_cvt_kernel<<<dim3(HW / 32, KC / 32, BATCH), 256, 0, stream>>>(k_ws, kT, KC);
    psp_pool_bf16_kernel<<<dim3(KC, BATCH), 128, 0, stream>>>(k_ws, keytb);
    value_kernel<<<dim3(SPV, BATCH), 256, 0, stream>>>(Wv, bv, px, valT);
    attn_mfma_kernel<<<dim3(HW / 64, BATCH), 256, 0, stream>>>(kT, keytb, valT, ctxT);
    // out = Ww @ ctx + bw : M=512, N=5184, K=256
    gemm_nt_bf16<<<dim3((HW + 127) / 128, CIN / 128, BATCH), 256, 0, stream>>>(
        Wwbf, ctxT, out, CIN, HW, VC, nullptr, bw, 0);
}

// Round 3
// 220.481 us; speedup vs baseline: 2.3811x; 1.2037x over previous
//
#include <hip/hip_runtime.h>
#include <hip/hip_bf16.h>

#define HW    5184
#define WIDTH 72
#define CIN   512
#define KC    256
#define VC    256
#define NS    110
#define NSP   112   // padded s for QK^T (7*16)
#define SPV   128   // padded s for PV k-dim (4*32)
#define BATCH 8

typedef unsigned short u16;
typedef unsigned int   u32;
typedef __attribute__((ext_vector_type(8))) short bf16x8;   // 8 bf16 = 4 VGPRs
typedef __attribute__((ext_vector_type(4))) float f32x4;

typedef const __attribute__((address_space(1))) u32* gp_t;
typedef __attribute__((address_space(3))) u32* lp_t;

__device__ __forceinline__ u32 f2bf1(float f) {
    u32 u = __float_as_uint(f);
    return (u + 0x7FFFu + ((u >> 16) & 1u)) >> 16;   // RNE
}
__device__ __forceinline__ u32 pack2(float a, float b) {
    return f2bf1(a) | (f2bf1(b) << 16);
}

// ---------------- prep: fold BN into per-channel scale/bias ----------------
__global__ void prep_kernel(const float* __restrict__ bk, const float* __restrict__ gamma,
                            const float* __restrict__ beta, const float* __restrict__ rmean,
                            const float* __restrict__ rvar, float* __restrict__ inv_out,
                            float* __restrict__ bc_out) {
    int i = threadIdx.x;  // 256 threads, one per Kc channel
    float inv = gamma[i] * rsqrtf(rvar[i] + 1e-5f);
    inv_out[i] = inv;
    bc_out[i]  = bk[i] * inv + beta[i] - rmean[i] * inv;
}

// ---------------- convert Wk/Ww/Wv fp32 -> bf16 ----------------
__global__ __launch_bounds__(256) void cvt_w_kernel(
    const float* __restrict__ Wk, const float* __restrict__ Ww, const float* __restrict__ Wv,
    u16* __restrict__ Wkbf, u16* __restrict__ Wwbf, u16* __restrict__ Wvbf)
{
    int j = (blockIdx.x * 256 + threadIdx.x) * 4;   // grid 384 -> 393216 elems
    const float* s; u16* d;
    if (j < KC * CIN)          { s = Wk; d = Wkbf; }
    else if (j < 2 * KC * CIN) { j -= KC * CIN;     s = Ww; d = Wwbf; }
    else                       { j -= 2 * KC * CIN; s = Wv; d = Wvbf; }
    float4 v = *(const float4*)&s[j];
    uint2 u;
    u.x = pack2(v.x, v.y);
    u.y = pack2(v.z, v.w);
    *(uint2*)&d[j] = u;
}

// ---------------- transpose+cvt: in [z][C][5184] f32 -> out [z][5184][C] bf16 ----------------
__global__ __launch_bounds__(256) void transpose_cvt_kernel(
    const float* __restrict__ in, u16* __restrict__ out, int C)
{
    const int z  = blockIdx.z;
    const int n0 = blockIdx.x * 32;   // HW
    const int k0 = blockIdx.y * 32;   // C
    __shared__ float t[32][33];
    const int tx = threadIdx.x & 31, ty = threadIdx.x >> 5;   // ty 0..7
    const float* src = in + ((size_t)z * C + k0) * HW + n0;
#pragma unroll
    for (int i = 0; i < 4; i++)
        t[ty + i * 8][tx] = src[(size_t)(ty + i * 8) * HW + tx];
    __syncthreads();
    u16* dst = out + ((size_t)z * HW + n0) * C + k0;
    const int kp  = (threadIdx.x & 15) * 2;
    const int nl0 = threadIdx.x >> 4;           // 0..15
#pragma unroll
    for (int j = 0; j < 2; j++) {
        int nl = nl0 + j * 16;
        u32 u = pack2(t[kp][nl], t[kp + 1][nl]);
        *(u32*)&dst[(size_t)nl * C + kp] = u;
    }
}

// ---------------- bf16 MFMA NT-GEMM: C[z][m][n] = sum_k A[m][k] * B[z][n][k] ----------------
__global__ __launch_bounds__(256) void gemm_nt_bf16(
    const u16* __restrict__ A, const u16* __restrict__ B, float* __restrict__ C,
    int M, int N, int K,
    const float* __restrict__ scale, const float* __restrict__ bias, int relu)
{
    const int n0 = blockIdx.x * 128;
    const int m0 = blockIdx.y * 128;
    const size_t boff = (size_t)blockIdx.z * N * K;
    const size_t coff = (size_t)blockIdx.z * M * N;
    const int tid  = threadIdx.x;
    const int wid  = tid >> 6;
    const int lane = tid & 63;

    __shared__ __align__(16) u16 As[4][128][8];   // 8 KB
    __shared__ __align__(16) u16 Bs[4][128][8];   // 8 KB

    const int kg0  = (wid & 1) * 2;
    const int half = (wid >> 1) * 64;

    const u16* gA = A + (size_t)(m0 + half + lane) * K + kg0 * 8;
    int nIdx = n0 + half + lane;
    if (nIdx > N - 1) nIdx = N - 1;               // clamp tail block (dup loads, stores masked)
    const u16* gB = B + boff + (size_t)nIdx * K + kg0 * 8;

    lp_t lA0 = (lp_t)&As[kg0][half][0];
    lp_t lA1 = (lp_t)&As[kg0 + 1][half][0];
    lp_t lB0 = (lp_t)&Bs[kg0][half][0];
    lp_t lB1 = (lp_t)&Bs[kg0 + 1][half][0];

    const int wm  = (wid >> 1) * 64;
    const int wn  = (wid & 1) * 64;
    const int l16 = lane & 15;
    const int lq  = lane >> 4;

    f32x4 acc[4][4];
#pragma unroll
    for (int mi = 0; mi < 4; mi++)
#pragma unroll
        for (int ni = 0; ni < 4; ni++)
            acc[mi][ni] = (f32x4){0.f, 0.f, 0.f, 0.f};

    for (int k0 = 0; k0 < K; k0 += 32) {
        __builtin_amdgcn_global_load_lds((gp_t)(gA + k0),     lA0, 16, 0, 0);
        __builtin_amdgcn_global_load_lds((gp_t)(gA + k0 + 8), lA1, 16, 0, 0);
        __builtin_amdgcn_global_load_lds((gp_t)(gB + k0),     lB0, 16, 0, 0);
        __builtin_amdgcn_global_load_lds((gp_t)(gB + k0 + 8), lB1, 16, 0, 0);
        __syncthreads();

        bf16x8 af[4], bf[4];
#pragma unroll
        for (int i = 0; i < 4; i++) {
            af[i] = *(const bf16x8*)&As[lq][wm + i * 16 + l16][0];
            bf[i] = *(const bf16x8*)&Bs[lq][wn + i * 16 + l16][0];
        }
#pragma unroll
        for (int mi = 0; mi < 4; mi++)
#pragma unroll
            for (int ni = 0; ni < 4; ni++)
                acc[mi][ni] = __builtin_amdgcn_mfma_f32_16x16x32_bf16(
                    af[mi], bf[ni], acc[mi][ni], 0, 0, 0);
        __syncthreads();
    }

#pragma unroll
    for (int mi = 0; mi < 4; mi++) {
        const int mb = m0 + wm + mi * 16 + lq * 4;
        float sc[4], bi[4];
#pragma unroll
        for (int r = 0; r < 4; r++) {
            sc[r] = scale ? scale[mb + r] : 1.0f;
            bi[r] = bias  ? bias[mb + r]  : 0.0f;
        }
#pragma unroll
        for (int ni = 0; ni < 4; ni++) {
            const int n = n0 + wn + ni * 16 + l16;
            if (n < N) {
#pragma unroll
                for (int r = 0; r < 4; r++) {
                    float v = acc[mi][ni][r] * sc[r] + bi[r];
                    if (relu) v = fmaxf(v, 0.f);
                    C[coff + (size_t)(mb + r) * N + n] = v;
                }
            }
        }
    }
}

// ---------------- value MFMA GEMM: valT[b][v][s] = bf16(Wv[v][:].px[b][s][:] + bv[v]) ----------------
// A = Wvbf [256][512], B = pxb [b][128][512] (pad rows zeroed), out stride SPV
__global__ __launch_bounds__(256) void value_mfma_kernel(
    const u16* __restrict__ A, const u16* __restrict__ Bp,
    const float* __restrict__ bv, u16* __restrict__ valT)
{
    const int m0 = blockIdx.x * 128;              // v-block (0 or 128)
    const int b  = blockIdx.y;
    const int tid  = threadIdx.x;
    const int wid  = tid >> 6;
    const int lane = tid & 63;

    __shared__ __align__(16) u16 As[4][128][8];
    __shared__ __align__(16) u16 Bs[4][128][8];

    const int kg0  = (wid & 1) * 2;
    const int half = (wid >> 1) * 64;

    const u16* gA = A + (size_t)(m0 + half + lane) * CIN + kg0 * 8;
    const u16* gB = Bp + (size_t)b * SPV * CIN + (size_t)(half + lane) * CIN + kg0 * 8;

    lp_t lA0 = (lp_t)&As[kg0][half][0];
    lp_t lA1 = (lp_t)&As[kg0 + 1][half][0];
    lp_t lB0 = (lp_t)&Bs[kg0][half][0];
    lp_t lB1 = (lp_t)&Bs[kg0 + 1][half][0];

    const int wm  = (wid >> 1) * 64;
    const int wn  = (wid & 1) * 64;
    const int l16 = lane & 15;
    const int lq  = lane >> 4;

    f32x4 acc[4][4];
#pragma unroll
    for (int mi = 0; mi < 4; mi++)
#pragma unroll
        for (int ni = 0; ni < 4; ni++)
            acc[mi][ni] = (f32x4){0.f, 0.f, 0.f, 0.f};

    for (int k0 = 0; k0 < CIN; k0 += 32) {
        __builtin_amdgcn_global_load_lds((gp_t)(gA + k0),     lA0, 16, 0, 0);
        __builtin_amdgcn_global_load_lds((gp_t)(gA + k0 + 8), lA1, 16, 0, 0);
        __builtin_amdgcn_global_load_lds((gp_t)(gB + k0),     lB0, 16, 0, 0);
        __builtin_amdgcn_global_load_lds((gp_t)(gB + k0 + 8), lB1, 16, 0, 0);
        __syncthreads();

        bf16x8 af[4], bf[4];
#pragma unroll
        for (int i = 0; i < 4; i++) {
            af[i] = *(const bf16x8*)&As[lq][wm + i * 16 + l16][0];
            bf[i] = *(const bf16x8*)&Bs[lq][wn + i * 16 + l16][0];
        }
#pragma unroll
        for (int mi = 0; mi < 4; mi++)
#pragma unroll
            for (int ni = 0; ni < 4; ni++)
                acc[mi][ni] = __builtin_amdgcn_mfma_f32_16x16x32_bf16(
                    af[mi], bf[ni], acc[mi][ni], 0, 0, 0);
        __syncthreads();
    }

#pragma unroll
    for (int mi = 0; mi < 4; mi++) {
        const int mb = m0 + wm + mi * 16 + lq * 4;
        float bi[4];
#pragma unroll
        for (int r = 0; r < 4; r++) bi[r] = bv[mb + r];
#pragma unroll
        for (int ni = 0; ni < 4; ni++) {
            const int n = wn + ni * 16 + l16;   // s index, 0..127
#pragma unroll
            for (int r = 0; r < 4; r++)
                valT[((size_t)b * VC + mb + r) * SPV + n] = (u16)f2bf1(acc[mi][ni][r] + bi[r]);
        }
    }
}

// ---------------- PSP pooling px: x [b][512][5184] f32 -> pxb [b][128][512] bf16 ----------------
__global__ __launch_bounds__(128) void psp_pool_px_kernel(
    const float* __restrict__ in, u16* __restrict__ out)
{
    const int c = blockIdx.x;   // 0..511
    const int b = blockIdx.y;
    const int t = threadIdx.x;
    __shared__ float4 row4[1296];
    __shared__ float aux[100];
    float* row = (float*)row4;
    const float* src = in + ((size_t)b * CIN + c) * HW;
    for (int idx = t; idx < 1296; idx += 128)
        row4[idx] = *(const float4*)(src + idx * 4);
    __syncthreads();
    if (t < 64) {
        int r0 = (t >> 3) * 9, c0 = (t & 7) * 9;
        float s = 0.f;
        for (int i = 0; i < 9; i++)
            for (int j = 0; j < 9; j++) s += row[(r0 + i) * WIDTH + c0 + j];
        aux[t] = s;
    } else if (t < 100) {
        int tt = t - 64;
        int r0 = (tt / 6) * 12, c0 = (tt % 6) * 12;
        float s = 0.f;
        for (int i = 0; i < 12; i++)
            for (int j = 0; j < 12; j++) s += row[(r0 + i) * WIDTH + c0 + j];
        aux[64 + tt] = s;
    }
    __syncthreads();
    u16* ob = out + (size_t)b * SPV * CIN + c;
    if (t < 64) ob[(size_t)(46 + t) * CIN] = (u16)f2bf1(aux[t] * (1.f / 81.f));
    if (t < 36) ob[(size_t)(10 + t) * CIN] = (u16)f2bf1(aux[64 + t] * (1.f / 144.f));
    if (t < 9) {
        int r = t / 3, cc = t % 3;
        float s4 = aux[64 + (2 * r) * 6 + 2 * cc] + aux[64 + (2 * r) * 6 + 2 * cc + 1]
                 + aux[64 + (2 * r + 1) * 6 + 2 * cc] + aux[64 + (2 * r + 1) * 6 + 2 * cc + 1];
        ob[(size_t)(1 + t) * CIN] = (u16)f2bf1(s4 * (1.f / 576.f));
    }
    if (t == 0) {
        float s = 0.f;
        for (int i = 0; i < 64; i++) s += aux[i];
        ob[0] = (u16)f2bf1(s * (1.f / 5184.f));
    }
    if (t < 18) ob[(size_t)(110 + t) * CIN] = 0;   // zero pad rows (NaN safety for value GEMM)
}

// ---------------- PSP pooling bf16: in [b][256][5184] -> out [b][112][256] bf16 ----------------
__global__ __launch_bounds__(128) void psp_pool_bf16_kernel(
    const float* __restrict__ in, u16* __restrict__ out)
{
    const int c = blockIdx.x;   // 0..255
    const int b = blockIdx.y;
    const int t = threadIdx.x;
    __shared__ float4 row4[1296];
    __shared__ float aux[100];
    float* row = (float*)row4;
    const float* src = in + ((size_t)b * KC + c) * HW;
    for (int idx = t; idx < 1296; idx += 128)
        row4[idx] = *(const float4*)(src + idx * 4);
    __syncthreads();
    if (t < 64) {
        int r0 = (t >> 3) * 9, c0 = (t & 7) * 9;
        float s = 0.f;
        for (int i = 0; i < 9; i++)
            for (int j = 0; j < 9; j++) s += row[(r0 + i) * WIDTH + c0 + j];
        aux[t] = s;
    } else if (t < 100) {
        int tt = t - 64;
        int r0 = (tt / 6) * 12, c0 = (tt % 6) * 12;
        float s = 0.f;
        for (int i = 0; i < 12; i++)
            for (int j = 0; j < 12; j++) s += row[(r0 + i) * WIDTH + c0 + j];
        aux[64 + tt] = s;
    }
    __syncthreads();
    u16* ob = out + (size_t)b * NSP * KC + c;
    if (t < 64) ob[(size_t)(46 + t) * KC] = (u16)f2bf1(aux[t] * (1.f / 81.f));
    if (t < 36) ob[(size_t)(10 + t) * KC] = (u16)f2bf1(aux[64 + t] * (1.f / 144.f));
    if (t < 9) {
        int r = t / 3, cc = t % 3;
        float s4 = aux[64 + (2 * r) * 6 + 2 * cc] + aux[64 + (2 * r) * 6 + 2 * cc + 1]
                 + aux[64 + (2 * r + 1) * 6 + 2 * cc] + aux[64 + (2 * r + 1) * 6 + 2 * cc + 1];
        ob[(size_t)(1 + t) * KC] = (u16)f2bf1(s4 * (1.f / 576.f));
    }
    if (t == 0) {
        float s = 0.f;
        for (int i = 0; i < 64; i++) s += aux[i];
        ob[0] = (u16)f2bf1(s * (1.f / 5184.f));
        ob[(size_t)110 * KC] = 0;   // zero pad rows (NaN safety)
        ob[(size_t)111 * KC] = 0;
    }
}

// ---------------- MFMA attention: 64 px/block, 4 waves x 16 px ----------------
// qT: [b][5184][256] bf16, keyt: [b][112][256] bf16, valT: [b][256][128] bf16
// ctxT out: [b][5184][256] bf16
__global__ __launch_bounds__(256) void attn_mfma_kernel(
    const u16* __restrict__ qT, const u16* __restrict__ keyt,
    const u16* __restrict__ valT, u16* __restrict__ ctxT)
{
    const int b    = blockIdx.y;
    const int tid  = threadIdx.x;
    const int wid  = tid >> 6;
    const int lane = tid & 63;
    const int l16  = lane & 15;
    const int lq   = lane >> 4;
    const int px0  = blockIdx.x * 64 + wid * 16;   // wave's 16-px row base

    __shared__ __align__(16) u16 P[64 * 128];      // XOR-swizzled [row][s] bf16, 16 KB
    char* Pb = (char*)P;

    // zero P (covers s>=112 pad; swizzle is a within-row permutation so linear zero is fine)
    {
        u32* p32 = (u32*)P;
#pragma unroll
        for (int i = 0; i < 16; i++) p32[tid + i * 256] = 0;
    }

    // ==== QK^T: acc[ni] is the 16x16 D tile (rows px 4*lq+r, cols s ni*16+l16) ====
    const u16* qrow = qT + ((size_t)b * HW + px0 + l16) * KC + lq * 8;
    const u16* krow = keyt + (size_t)b * NSP * KC + lq * 8;
    f32x4 acc[7];
#pragma unroll
    for (int ni = 0; ni < 7; ni++) acc[ni] = (f32x4){0.f, 0.f, 0.f, 0.f};
#pragma unroll
    for (int ks = 0; ks < 8; ks++) {
        bf16x8 aq = *(const bf16x8*)(qrow + ks * 32);
#pragma unroll
        for (int ni = 0; ni < 7; ni++) {
            bf16x8 bk = *(const bf16x8*)(krow + (size_t)(ni * 16 + l16) * KC + ks * 32);
            acc[ni] = __builtin_amdgcn_mfma_f32_16x16x32_bf16(aq, bk, acc[ni], 0, 0, 0);
        }
    }

    // mask pad columns s=110,111 (ni=6, l16>=14)
    if (l16 >= 14) acc[6] = (f32x4){-1e30f, -1e30f, -1e30f, -1e30f};

    // ==== softmax over s (in-register; row r's s-values live across 16 lanes x 7 regs) ====
    float mx[4], sm[4], rn[4];
#pragma unroll
    for (int r = 0; r < 4; r++) {
        float m = acc[0][r];
#pragma unroll
        for (int ni = 1; ni < 7; ni++) m = fmaxf(m, acc[ni][r]);
        m = fmaxf(m, __shfl_xor(m, 1));
        m = fmaxf(m, __shfl_xor(m, 2));
        m = fmaxf(m, __shfl_xor(m, 4));
        m = fmaxf(m, __shfl_xor(m, 8));
        mx[r] = m * 0.0625f;     // fold Kc^-0.5
        sm[r] = 0.f;
    }

    __syncthreads();   // P zero done (cross-wave) before P writes

    const int prow = wid * 16 + 4 * lq;
#pragma unroll
    for (int ni = 0; ni < 7; ni++) {
#pragma unroll
        for (int r = 0; r < 4; r++) {
            float p = __expf(acc[ni][r] * 0.0625f - mx[r]);   // masked cols -> exp(-huge)=0
            sm[r] += p;
            const int row = prow + r;
            int byte = row * 256 + (ni * 16 + l16) * 2;
            byte ^= (row & 7) << 4;
            *(u16*)(Pb + byte) = (u16)f2bf1(p);
        }
    }
#pragma unroll
    for (int r = 0; r < 4; r++) {
        float s = sm[r];
        s += __shfl_xor(s, 1);
        s += __shfl_xor(s, 2);
        s += __shfl_xor(s, 4);
        s += __shfl_xor(s, 8);
        rn[r] = 1.f / s;
    }

    __syncthreads();   // P writes visible

    // ==== PV: ctx[px][v] = sum_s P[px][s] * valT[v][s] ====
    f32x4 acc2[16];
#pragma unroll
    for (int ni = 0; ni < 16; ni++) acc2[ni] = (f32x4){0.f, 0.f, 0.f, 0.f};
    const u16* vrow = valT + ((size_t)b * VC + l16) * SPV + lq * 8;
    const int arow = wid * 16 + l16;
    const int aswz = (arow & 7) << 4;
#pragma unroll
    for (int ks = 0; ks < 4; ks++) {
        int byte = arow * 256 + ks * 64 + lq * 16;
        byte ^= aswz;
        bf16x8 pa = *(const bf16x8*)(Pb + byte);
#pragma unroll
        for (int ni = 0; ni < 16; ni++) {
            bf16x8 bv = *(const bf16x8*)(vrow + (size_t)ni * 16 * SPV + ks * 32);
            acc2[ni] = __builtin_amdgcn_mfma_f32_16x16x32_bf16(pa, bv, acc2[ni], 0, 0, 0);
        }
    }

    // epilogue: normalize by row sum, write ctxT[b][px][v] bf16
    u16* crow = ctxT + ((size_t)b * HW + px0 + 4 * lq) * VC + l16;
#pragma unroll
    for (int ni = 0; ni < 16; ni++) {
#pragma unroll
        for (int r = 0; r < 4; r++) {
            float v = acc2[ni][r] * rn[r];
            crow[(size_t)r * VC + ni * 16] = (u16)f2bf1(v);
        }
    }
}

extern "C" void kernel_launch(void* const* d_in, const int* in_sizes, int n_in,
                              void* d_out, int out_size, void* d_ws, size_t ws_size,
                              hipStream_t stream)
{
    const float* x     = (const float*)d_in[0];
    const float* Wk    = (const float*)d_in[1];
    const float* bk    = (const float*)d_in[2];
    const float* gamma = (const float*)d_in[3];
    const float* beta  = (const float*)d_in[4];
    const float* rmean = (const float*)d_in[5];
    const float* rvar  = (const float*)d_in[6];
    const float* Wv    = (const float*)d_in[7];
    const float* bv    = (const float*)d_in[8];
    const float* Ww    = (const float*)d_in[9];
    const float* bw    = (const float*)d_in[10];
    float* out = (float*)d_out;

    float* ws    = (float*)d_ws;
    float* k_ws  = ws;                                        // [8][256][5184] f32
    u16*   xT    = (u16*)(k_ws + (size_t)BATCH * KC * HW);    // [8][5184][512] bf16
    u16*   kT    = xT;                                        // alias (xT dead after gemm1): [8][5184][256]
    u16*   ctxT  = xT + (size_t)BATCH * HW * KC;              // alias second half: [8][5184][256]
    u16*   pxb   = xT + (size_t)BATCH * HW * CIN;             // [8][128][512] bf16
    u16*   keytb = pxb + (size_t)BATCH * SPV * CIN;           // [8][112][256] bf16
    u16*   valT  = keytb + (size_t)BATCH * NSP * KC;          // [8][256][128] bf16
    u16*   Wkbf  = valT + (size_t)BATCH * VC * SPV;           // [256][512] bf16
    u16*   Wwbf  = Wkbf + (size_t)KC * CIN;                   // [512][256] bf16
    u16*   Wvbf  = Wwbf + (size_t)CIN * VC;                   // [256][512] bf16
    float* inv   = (float*)(Wvbf + (size_t)KC * CIN);         // [256]
    float* bc    = inv + 256;                                 // [256]

    prep_kernel<<<1, 256, 0, stream>>>(bk, gamma, beta, rmean, rvar, inv, bc);
    cvt_w_kernel<<<384, 256, 0, stream>>>(Wk, Ww, Wv, Wkbf, Wwbf, Wvbf);
    psp_pool_px_kernel<<<dim3(CIN, BATCH), 128, 0, stream>>>(x, pxb);
    transpose_cvt_kernel<<<dim3(HW / 32, CIN / 32, BATCH), 256, 0, stream>>>(x, xT, CIN);
    // k = relu(BN(Wk @ x)) : M=256, N=5184, K=512
    gemm_nt_bf16<<<dim3((HW + 127) / 128, KC / 128, BATCH), 256, 0, stream>>>(
        Wkbf, xT, k_ws, KC, HW, CIN, inv, bc, 1);
    // kT (= qT) bf16 for attention A operand
    transpose_cvt_kernel<<<dim3(HW / 32, KC / 32, BATCH), 256, 0, stream>>>(k_ws, kT, KC);
    psp_pool_bf16_kernel<<<dim3(KC, BATCH), 128, 0, stream>>>(k_ws, keytb);
    value_mfma_kernel<<<dim3(2, BATCH), 256, 0, stream>>>(Wvbf, pxb, bv, valT);
    attn_mfma_kernel<<<dim3(HW / 64, BATCH), 256, 0, stream>>>(kT, keytb, valT, ctxT);
    // out = Ww @ ctx + bw : M=512, N=5184, K=256
    gemm_nt_bf16<<<dim3((HW + 127) / 128, CIN / 128, BATCH), 256, 0, stream>>>(
        Wwbf, ctxT, out, CIN, HW, VC, nullptr, bw, 0);
}

// Round 4
// 195.656 us; speedup vs baseline: 2.6832x; 1.1269x over previous
//
#include <hip/hip_runtime.h>
#include <hip/hip_bf16.h>

#define HW    5184
#define WIDTH 72
#define CIN   512
#define KC    256
#define VC    256
#define NS    110
#define NSP   112   // padded s for QK^T (7*16)
#define SPV   128   // padded s for PV k-dim (4*32)
#define BATCH 8

typedef unsigned short u16;
typedef unsigned int   u32;
typedef __attribute__((ext_vector_type(8))) short bf16x8;   // 8 bf16 = 4 VGPRs
typedef __attribute__((ext_vector_type(4))) float f32x4;

typedef const __attribute__((address_space(1))) u32* gp_t;
typedef __attribute__((address_space(3))) u32* lp_t;

__device__ __forceinline__ u32 f2bf1(float f) {
    u32 u = __float_as_uint(f);
    return (u + 0x7FFFu + ((u >> 16) & 1u)) >> 16;   // RNE
}
__device__ __forceinline__ u32 pack2(float a, float b) {
    return f2bf1(a) | (f2bf1(b) << 16);
}

// ---------------- prep: fold BN into per-channel scale/bias ----------------
__global__ void prep_kernel(const float* __restrict__ bk, const float* __restrict__ gamma,
                            const float* __restrict__ beta, const float* __restrict__ rmean,
                            const float* __restrict__ rvar, float* __restrict__ inv_out,
                            float* __restrict__ bc_out) {
    int i = threadIdx.x;  // 256 threads, one per Kc channel
    float inv = gamma[i] * rsqrtf(rvar[i] + 1e-5f);
    inv_out[i] = inv;
    bc_out[i]  = bk[i] * inv + beta[i] - rmean[i] * inv;
}

// ---------------- convert Wk/Ww/Wv fp32 -> bf16 ----------------
__global__ __launch_bounds__(256) void cvt_w_kernel(
    const float* __restrict__ Wk, const float* __restrict__ Ww, const float* __restrict__ Wv,
    u16* __restrict__ Wkbf, u16* __restrict__ Wwbf, u16* __restrict__ Wvbf)
{
    int j = (blockIdx.x * 256 + threadIdx.x) * 4;   // grid 384 -> 393216 elems
    const float* s; u16* d;
    if (j < KC * CIN)          { s = Wk; d = Wkbf; }
    else if (j < 2 * KC * CIN) { j -= KC * CIN;     s = Ww; d = Wwbf; }
    else                       { j -= 2 * KC * CIN; s = Wv; d = Wvbf; }
    float4 v = *(const float4*)&s[j];
    uint2 u;
    u.x = pack2(v.x, v.y);
    u.y = pack2(v.z, v.w);
    *(uint2*)&d[j] = u;
}

// ---------------- transpose+cvt: in [z][C][5184] f32 -> out [z][5184][C] bf16 ----------------
__global__ __launch_bounds__(256) void transpose_cvt_kernel(
    const float* __restrict__ in, u16* __restrict__ out, int C)
{
    const int z  = blockIdx.z;
    const int n0 = blockIdx.x * 32;   // HW
    const int k0 = blockIdx.y * 32;   // C
    __shared__ float t[32][33];
    const int tx = threadIdx.x & 31, ty = threadIdx.x >> 5;   // ty 0..7
    const float* src = in + ((size_t)z * C + k0) * HW + n0;
#pragma unroll
    for (int i = 0; i < 4; i++)
        t[ty + i * 8][tx] = src[(size_t)(ty + i * 8) * HW + tx];
    __syncthreads();
    u16* dst = out + ((size_t)z * HW + n0) * C + k0;
    const int kp  = (threadIdx.x & 15) * 2;
    const int nl0 = threadIdx.x >> 4;           // 0..15
#pragma unroll
    for (int j = 0; j < 2; j++) {
        int nl = nl0 + j * 16;
        u32 u = pack2(t[kp][nl], t[kp + 1][nl]);
        *(u32*)&dst[(size_t)nl * C + kp] = u;
    }
}

// ---------------- bf16 MFMA NT-GEMM: C[z][m][n] = sum_k A[m][k] * B[z][n][k] ----------------
__global__ __launch_bounds__(256) void gemm_nt_bf16(
    const u16* __restrict__ A, const u16* __restrict__ B, float* __restrict__ C,
    int M, int N, int K,
    const float* __restrict__ scale, const float* __restrict__ bias, int relu)
{
    const int n0 = blockIdx.x * 128;
    const int m0 = blockIdx.y * 128;
    const size_t boff = (size_t)blockIdx.z * N * K;
    const size_t coff = (size_t)blockIdx.z * M * N;
    const int tid  = threadIdx.x;
    const int wid  = tid >> 6;
    const int lane = tid & 63;

    __shared__ __align__(16) u16 As[4][128][8];   // 8 KB
    __shared__ __align__(16) u16 Bs[4][128][8];   // 8 KB

    const int kg0  = (wid & 1) * 2;
    const int half = (wid >> 1) * 64;

    const u16* gA = A + (size_t)(m0 + half + lane) * K + kg0 * 8;
    int nIdx = n0 + half + lane;
    if (nIdx > N - 1) nIdx = N - 1;               // clamp tail block (dup loads, stores masked)
    const u16* gB = B + boff + (size_t)nIdx * K + kg0 * 8;

    lp_t lA0 = (lp_t)&As[kg0][half][0];
    lp_t lA1 = (lp_t)&As[kg0 + 1][half][0];
    lp_t lB0 = (lp_t)&Bs[kg0][half][0];
    lp_t lB1 = (lp_t)&Bs[kg0 + 1][half][0];

    const int wm  = (wid >> 1) * 64;
    const int wn  = (wid & 1) * 64;
    const int l16 = lane & 15;
    const int lq  = lane >> 4;

    f32x4 acc[4][4];
#pragma unroll
    for (int mi = 0; mi < 4; mi++)
#pragma unroll
        for (int ni = 0; ni < 4; ni++)
            acc[mi][ni] = (f32x4){0.f, 0.f, 0.f, 0.f};

    for (int k0 = 0; k0 < K; k0 += 32) {
        __builtin_amdgcn_global_load_lds((gp_t)(gA + k0),     lA0, 16, 0, 0);
        __builtin_amdgcn_global_load_lds((gp_t)(gA + k0 + 8), lA1, 16, 0, 0);
        __builtin_amdgcn_global_load_lds((gp_t)(gB + k0),     lB0, 16, 0, 0);
        __builtin_amdgcn_global_load_lds((gp_t)(gB + k0 + 8), lB1, 16, 0, 0);
        __syncthreads();

        bf16x8 af[4], bf[4];
#pragma unroll
        for (int i = 0; i < 4; i++) {
            af[i] = *(const bf16x8*)&As[lq][wm + i * 16 + l16][0];
            bf[i] = *(const bf16x8*)&Bs[lq][wn + i * 16 + l16][0];
        }
#pragma unroll
        for (int mi = 0; mi < 4; mi++)
#pragma unroll
            for (int ni = 0; ni < 4; ni++)
                acc[mi][ni] = __builtin_amdgcn_mfma_f32_16x16x32_bf16(
                    af[mi], bf[ni], acc[mi][ni], 0, 0, 0);
        __syncthreads();
    }

#pragma unroll
    for (int mi = 0; mi < 4; mi++) {
        const int mb = m0 + wm + mi * 16 + lq * 4;
        float sc[4], bi[4];
#pragma unroll
        for (int r = 0; r < 4; r++) {
            sc[r] = scale ? scale[mb + r] : 1.0f;
            bi[r] = bias  ? bias[mb + r]  : 0.0f;
        }
#pragma unroll
        for (int ni = 0; ni < 4; ni++) {
            const int n = n0 + wn + ni * 16 + l16;
            if (n < N) {
#pragma unroll
                for (int r = 0; r < 4; r++) {
                    float v = acc[mi][ni][r] * sc[r] + bi[r];
                    if (relu) v = fmaxf(v, 0.f);
                    C[coff + (size_t)(mb + r) * N + n] = v;
                }
            }
        }
    }
}

// ---------------- value MFMA GEMM: valT (SWIZZLED) [b][v][s] bf16 ----------------
// A = Wvbf [256][512], B = pxb [b][128][512] (pad rows zeroed)
// Write layout: within-batch byte = v*256 + ((s*2) ^ ((v&7)<<4))  [matches attn LDS reads]
__global__ __launch_bounds__(256) void value_mfma_kernel(
    const u16* __restrict__ A, const u16* __restrict__ Bp,
    const float* __restrict__ bv, u16* __restrict__ valT)
{
    const int m0 = blockIdx.x * 128;              // v-block (0 or 128)
    const int b  = blockIdx.y;
    const int tid  = threadIdx.x;
    const int wid  = tid >> 6;
    const int lane = tid & 63;

    __shared__ __align__(16) u16 As[4][128][8];
    __shared__ __align__(16) u16 Bs[4][128][8];

    const int kg0  = (wid & 1) * 2;
    const int half = (wid >> 1) * 64;

    const u16* gA = A + (size_t)(m0 + half + lane) * CIN + kg0 * 8;
    const u16* gB = Bp + (size_t)b * SPV * CIN + (size_t)(half + lane) * CIN + kg0 * 8;

    lp_t lA0 = (lp_t)&As[kg0][half][0];
    lp_t lA1 = (lp_t)&As[kg0 + 1][half][0];
    lp_t lB0 = (lp_t)&Bs[kg0][half][0];
    lp_t lB1 = (lp_t)&Bs[kg0 + 1][half][0];

    const int wm  = (wid >> 1) * 64;
    const int wn  = (wid & 1) * 64;
    const int l16 = lane & 15;
    const int lq  = lane >> 4;

    f32x4 acc[4][4];
#pragma unroll
    for (int mi = 0; mi < 4; mi++)
#pragma unroll
        for (int ni = 0; ni < 4; ni++)
            acc[mi][ni] = (f32x4){0.f, 0.f, 0.f, 0.f};

    for (int k0 = 0; k0 < CIN; k0 += 32) {
        __builtin_amdgcn_global_load_lds((gp_t)(gA + k0),     lA0, 16, 0, 0);
        __builtin_amdgcn_global_load_lds((gp_t)(gA + k0 + 8), lA1, 16, 0, 0);
        __builtin_amdgcn_global_load_lds((gp_t)(gB + k0),     lB0, 16, 0, 0);
        __builtin_amdgcn_global_load_lds((gp_t)(gB + k0 + 8), lB1, 16, 0, 0);
        __syncthreads();

        bf16x8 af[4], bf[4];
#pragma unroll
        for (int i = 0; i < 4; i++) {
            af[i] = *(const bf16x8*)&As[lq][wm + i * 16 + l16][0];
            bf[i] = *(const bf16x8*)&Bs[lq][wn + i * 16 + l16][0];
        }
#pragma unroll
        for (int mi = 0; mi < 4; mi++)
#pragma unroll
            for (int ni = 0; ni < 4; ni++)
                acc[mi][ni] = __builtin_amdgcn_mfma_f32_16x16x32_bf16(
                    af[mi], bf[ni], acc[mi][ni], 0, 0, 0);
        __syncthreads();
    }

    char* vb = (char*)valT + (size_t)b * VC * SPV * 2;
#pragma unroll
    for (int mi = 0; mi < 4; mi++) {
        const int mb = m0 + wm + mi * 16 + lq * 4;
        float bi[4];
#pragma unroll
        for (int r = 0; r < 4; r++) bi[r] = bv[mb + r];
#pragma unroll
        for (int ni = 0; ni < 4; ni++) {
            const int n = wn + ni * 16 + l16;   // s index, 0..127
#pragma unroll
            for (int r = 0; r < 4; r++) {
                const int v = mb + r;
                const int byte = v * 256 + ((n * 2) ^ ((v & 7) << 4));
                *(u16*)(vb + byte) = (u16)f2bf1(acc[mi][ni][r] + bi[r]);
            }
        }
    }
}

// ---------------- PSP pooling px: x [b][512][5184] f32 -> pxb [b][128][512] bf16 ----------------
__global__ __launch_bounds__(128) void psp_pool_px_kernel(
    const float* __restrict__ in, u16* __restrict__ out)
{
    const int c = blockIdx.x;   // 0..511
    const int b = blockIdx.y;
    const int t = threadIdx.x;
    __shared__ float4 row4[1296];
    __shared__ float aux[100];
    float* row = (float*)row4;
    const float* src = in + ((size_t)b * CIN + c) * HW;
    for (int idx = t; idx < 1296; idx += 128)
        row4[idx] = *(const float4*)(src + idx * 4);
    __syncthreads();
    if (t < 64) {
        int r0 = (t >> 3) * 9, c0 = (t & 7) * 9;
        float s = 0.f;
        for (int i = 0; i < 9; i++)
            for (int j = 0; j < 9; j++) s += row[(r0 + i) * WIDTH + c0 + j];
        aux[t] = s;
    } else if (t < 100) {
        int tt = t - 64;
        int r0 = (tt / 6) * 12, c0 = (tt % 6) * 12;
        float s = 0.f;
        for (int i = 0; i < 12; i++)
            for (int j = 0; j < 12; j++) s += row[(r0 + i) * WIDTH + c0 + j];
        aux[64 + tt] = s;
    }
    __syncthreads();
    u16* ob = out + (size_t)b * SPV * CIN + c;
    if (t < 64) ob[(size_t)(46 + t) * CIN] = (u16)f2bf1(aux[t] * (1.f / 81.f));
    if (t < 36) ob[(size_t)(10 + t) * CIN] = (u16)f2bf1(aux[64 + t] * (1.f / 144.f));
    if (t < 9) {
        int r = t / 3, cc = t % 3;
        float s4 = aux[64 + (2 * r) * 6 + 2 * cc] + aux[64 + (2 * r) * 6 + 2 * cc + 1]
                 + aux[64 + (2 * r + 1) * 6 + 2 * cc] + aux[64 + (2 * r + 1) * 6 + 2 * cc + 1];
        ob[(size_t)(1 + t) * CIN] = (u16)f2bf1(s4 * (1.f / 576.f));
    }
    if (t == 0) {
        float s = 0.f;
        for (int i = 0; i < 64; i++) s += aux[i];
        ob[0] = (u16)f2bf1(s * (1.f / 5184.f));
    }
    if (t < 18) ob[(size_t)(110 + t) * CIN] = 0;   // zero pad rows (NaN safety for value GEMM)
}

// ---------------- PSP pooling bf16 (SWIZZLED): k [b][256][5184] -> keyt [b][112][256] ----------------
// Write layout: within-batch byte = s*512 + ((c*2) ^ ((s&7)<<4))  [matches attn LDS reads]
__global__ __launch_bounds__(128) void psp_pool_bf16_kernel(
    const float* __restrict__ in, u16* __restrict__ out)
{
    const int c = blockIdx.x;   // 0..255
    const int b = blockIdx.y;
    const int t = threadIdx.x;
    __shared__ float4 row4[1296];
    __shared__ float aux[100];
    float* row = (float*)row4;
    const float* src = in + ((size_t)b * KC + c) * HW;
    for (int idx = t; idx < 1296; idx += 128)
        row4[idx] = *(const float4*)(src + idx * 4);
    __syncthreads();
    if (t < 64) {
        int r0 = (t >> 3) * 9, c0 = (t & 7) * 9;
        float s = 0.f;
        for (int i = 0; i < 9; i++)
            for (int j = 0; j < 9; j++) s += row[(r0 + i) * WIDTH + c0 + j];
        aux[t] = s;
    } else if (t < 100) {
        int tt = t - 64;
        int r0 = (tt / 6) * 12, c0 = (tt % 6) * 12;
        float s = 0.f;
        for (int i = 0; i < 12; i++)
            for (int j = 0; j < 12; j++) s += row[(r0 + i) * WIDTH + c0 + j];
        aux[64 + tt] = s;
    }
    __syncthreads();
    char* ob = (char*)out + (size_t)b * NSP * KC * 2;
    const int c2 = c * 2;
#define KWR(S, V) *(u16*)(ob + (S) * 512 + (c2 ^ (((S) & 7) << 4))) = (u16)f2bf1(V)
    if (t < 64) KWR(46 + t, aux[t] * (1.f / 81.f));
    if (t < 36) KWR(10 + t, aux[64 + t] * (1.f / 144.f));
    if (t < 9) {
        int r = t / 3, cc = t % 3;
        float s4 = aux[64 + (2 * r) * 6 + 2 * cc] + aux[64 + (2 * r) * 6 + 2 * cc + 1]
                 + aux[64 + (2 * r + 1) * 6 + 2 * cc] + aux[64 + (2 * r + 1) * 6 + 2 * cc + 1];
        KWR(1 + t, s4 * (1.f / 576.f));
    }
    if (t == 0) {
        float s = 0.f;
        for (int i = 0; i < 64; i++) s += aux[i];
        KWR(0, s * (1.f / 5184.f));
        KWR(110, 0.f);   // zero pad rows
        KWR(111, 0.f);
    }
#undef KWR
}

// ---------------- MFMA attention: 64 px/block, 4 waves x 16 px; K/V LDS-staged ----------------
// qT: [b][5184][256] bf16 (linear), keyt: [b][112][256] bf16 SWIZZLED,
// valT: [b][256][128] bf16 SWIZZLED, ctxT out: [b][5184][256] bf16 (linear)
__global__ __launch_bounds__(256) void attn_mfma_kernel(
    const u16* __restrict__ qT, const u16* __restrict__ keyt,
    const u16* __restrict__ valT, u16* __restrict__ ctxT)
{
    const int b    = blockIdx.y;
    const int tid  = threadIdx.x;
    const int wid  = tid >> 6;
    const int lane = tid & 63;
    const int l16  = lane & 15;
    const int lq   = lane >> 4;
    const int px0  = blockIdx.x * 64 + wid * 16;   // wave's 16-px row base

    // LDS: K (swizzled rows of 512B) at byte 0..57343; V (swizzled rows of 256B) at 57344..122879.
    // P [64][256B] overlays the K region after QK^T (barrier-protected).
    __shared__ __align__(16) u16 SM[61440];        // 122880 B -> 1 block/CU
    char* base = (char*)SM;
    const int VOFF = 57344;

    // ---- stage K and V (linear copy; global layout already swizzled) ----
    {
        const char* gk = (const char*)keyt + (size_t)b * (NSP * KC * 2);
        const char* gv = (const char*)valT + (size_t)b * (VC * SPV * 2);
#pragma unroll
        for (int i = 0; i < 14; i++) {             // K: 56 KiB = 4 waves x 14 x 1 KiB
            const int o = (wid * 14 + i) * 1024;
            __builtin_amdgcn_global_load_lds((gp_t)(gk + o + lane * 16), (lp_t)(base + o), 16, 0, 0);
        }
#pragma unroll
        for (int i = 0; i < 16; i++) {             // V: 64 KiB = 4 waves x 16 x 1 KiB
            const int o = (wid * 16 + i) * 1024;
            __builtin_amdgcn_global_load_lds((gp_t)(gv + o + lane * 16), (lp_t)(base + VOFF + o), 16, 0, 0);
        }
    }

    // ---- preload all 8 q fragments (overlaps with staging drain) ----
    const u16* qrow = qT + ((size_t)b * HW + px0 + l16) * KC + lq * 8;
    bf16x8 aq[8];
#pragma unroll
    for (int ks = 0; ks < 8; ks++) aq[ks] = *(const bf16x8*)(qrow + ks * 32);

    __syncthreads();   // staging complete (vmcnt drained at barrier)

    // ==== QK^T from LDS: acc[ni] rows px 4*lq+r, cols s ni*16+l16 ====
    f32x4 acc[7];
#pragma unroll
    for (int ni = 0; ni < 7; ni++) acc[ni] = (f32x4){0.f, 0.f, 0.f, 0.f};
#pragma unroll
    for (int ks = 0; ks < 8; ks++) {
#pragma unroll
        for (int ni = 0; ni < 7; ni++) {
            const int s = ni * 16 + l16;
            const int byte = s * 512 + ((ks * 64 + lq * 16) ^ ((s & 7) << 4));
            bf16x8 bk = *(const bf16x8*)(base + byte);
            acc[ni] = __builtin_amdgcn_mfma_f32_16x16x32_bf16(aq[ks], bk, acc[ni], 0, 0, 0);
        }
    }

    // mask pad columns s=110,111 (ni=6, l16>=14)
    if (l16 >= 14) acc[6] = (f32x4){-1e30f, -1e30f, -1e30f, -1e30f};

    // ==== softmax over s (in-register) ====
    float mx[4], sm[4], rn[4];
#pragma unroll
    for (int r = 0; r < 4; r++) {
        float m = acc[0][r];
#pragma unroll
        for (int ni = 1; ni < 7; ni++) m = fmaxf(m, acc[ni][r]);
        m = fmaxf(m, __shfl_xor(m, 1));
        m = fmaxf(m, __shfl_xor(m, 2));
        m = fmaxf(m, __shfl_xor(m, 4));
        m = fmaxf(m, __shfl_xor(m, 8));
        mx[r] = m * 0.0625f;     // fold Kc^-0.5
        sm[r] = 0.f;
    }

    __syncthreads();   // ALL waves done reading K -> safe to overlay P on K region

    const int prow = wid * 16 + 4 * lq;
#pragma unroll
    for (int ni = 0; ni < 7; ni++) {
#pragma unroll
        for (int r = 0; r < 4; r++) {
            float p = __expf(acc[ni][r] * 0.0625f - mx[r]);   // masked cols -> 0
            sm[r] += p;
            const int row = prow + r;
            const int byte = row * 256 + (((ni * 16 + l16) * 2) ^ ((row & 7) << 4));
            *(u16*)(base + byte) = (u16)f2bf1(p);
        }
    }
    // zero pad cols 112..127 (2 x 16B per row)
    if (l16 < 2) {
#pragma unroll
        for (int r = 0; r < 4; r++) {
            const int row = prow + r;
            const int byte = row * 256 + ((224 + l16 * 16) ^ ((row & 7) << 4));
            *(bf16x8*)(base + byte) = (bf16x8){0, 0, 0, 0, 0, 0, 0, 0};
        }
    }
#pragma unroll
    for (int r = 0; r < 4; r++) {
        float s = sm[r];
        s += __shfl_xor(s, 1);
        s += __shfl_xor(s, 2);
        s += __shfl_xor(s, 4);
        s += __shfl_xor(s, 8);
        rn[r] = 1.f / s;
    }

    __syncthreads();   // P visible

    // ==== PV from LDS: ctx[px][v] = sum_s P[px][s] * V[v][s] ====
    f32x4 acc2[16];
#pragma unroll
    for (int ni = 0; ni < 16; ni++) acc2[ni] = (f32x4){0.f, 0.f, 0.f, 0.f};
    const int arow = wid * 16 + l16;
    const int aswz = (arow & 7) << 4;
#pragma unroll
    for (int ks = 0; ks < 4; ks++) {
        const int pbyte = arow * 256 + ((ks * 64 + lq * 16) ^ aswz);
        bf16x8 pa = *(const bf16x8*)(base + pbyte);
#pragma unroll
        for (int ni = 0; ni < 16; ni++) {
            const int v = ni * 16 + l16;
            const int vbyte = VOFF + v * 256 + ((ks * 64 + lq * 16) ^ ((v & 7) << 4));
            bf16x8 bvv = *(const bf16x8*)(base + vbyte);
            acc2[ni] = __builtin_amdgcn_mfma_f32_16x16x32_bf16(pa, bvv, acc2[ni], 0, 0, 0);
        }
    }

    // epilogue: normalize by row sum, write ctxT[b][px][v] bf16
    u16* crow = ctxT + ((size_t)b * HW + px0 + 4 * lq) * VC + l16;
#pragma unroll
    for (int ni = 0; ni < 16; ni++) {
#pragma unroll
        for (int r = 0; r < 4; r++) {
            float v = acc2[ni][r] * rn[r];
            crow[(size_t)r * VC + ni * 16] = (u16)f2bf1(v);
        }
    }
}

extern "C" void kernel_launch(void* const* d_in, const int* in_sizes, int n_in,
                              void* d_out, int out_size, void* d_ws, size_t ws_size,
                              hipStream_t stream)
{
    const float* x     = (const float*)d_in[0];
    const float* Wk    = (const float*)d_in[1];
    const float* bk    = (const float*)d_in[2];
    const float* gamma = (const float*)d_in[3];
    const float* beta  = (const float*)d_in[4];
    const float* rmean = (const float*)d_in[5];
    const float* rvar  = (const float*)d_in[6];
    const float* Wv    = (const float*)d_in[7];
    const float* bv    = (const float*)d_in[8];
    const float* Ww    = (const float*)d_in[9];
    const float* bw    = (const float*)d_in[10];
    float* out = (float*)d_out;

    float* ws    = (float*)d_ws;
    float* k_ws  = ws;                                        // [8][256][5184] f32
    u16*   xT    = (u16*)(k_ws + (size_t)BATCH * KC * HW);    // [8][5184][512] bf16
    u16*   kT    = xT;                                        // alias (xT dead after gemm1): [8][5184][256]
    u16*   ctxT  = xT + (size_t)BATCH * HW * KC;              // alias second half: [8][5184][256]
    u16*   pxb   = xT + (size_t)BATCH * HW * CIN;             // [8][128][512] bf16
    u16*   keytb = pxb + (size_t)BATCH * SPV * CIN;           // [8][112][256] bf16 (swizzled)
    u16*   valT  = keytb + (size_t)BATCH * NSP * KC;          // [8][256][128] bf16 (swizzled)
    u16*   Wkbf  = valT + (size_t)BATCH * VC * SPV;           // [256][512] bf16
    u16*   Wwbf  = Wkbf + (size_t)KC * CIN;                   // [512][256] bf16
    u16*   Wvbf  = Wwbf + (size_t)CIN * VC;                   // [256][512] bf16
    float* inv   = (float*)(Wvbf + (size_t)KC * CIN);         // [256]
    float* bc    = inv + 256;                                 // [256]

    prep_kernel<<<1, 256, 0, stream>>>(bk, gamma, beta, rmean, rvar, inv, bc);
    cvt_w_kernel<<<384, 256, 0, stream>>>(Wk, Ww, Wv, Wkbf, Wwbf, Wvbf);
    psp_pool_px_kernel<<<dim3(CIN, BATCH), 128, 0, stream>>>(x, pxb);
    transpose_cvt_kernel<<<dim3(HW / 32, CIN / 32, BATCH), 256, 0, stream>>>(x, xT, CIN);
    // k = relu(BN(Wk @ x)) : M=256, N=5184, K=512
    gemm_nt_bf16<<<dim3((HW + 127) / 128, KC / 128, BATCH), 256, 0, stream>>>(
        Wkbf, xT, k_ws, KC, HW, CIN, inv, bc, 1);
    // kT (= qT) bf16 for attention A operand
    transpose_cvt_kernel<<<dim3(HW / 32, KC / 32, BATCH), 256, 0, stream>>>(k_ws, kT, KC);
    psp_pool_bf16_kernel<<<dim3(KC, BATCH), 128, 0, stream>>>(k_ws, keytb);
    value_mfma_kernel<<<dim3(2, BATCH), 256, 0, stream>>>(Wvbf, pxb, bv, valT);
    attn_mfma_kernel<<<dim3(HW / 64, BATCH), 256, 0, stream>>>(kT, keytb, valT, ctxT);
    // out = Ww @ ctx + bw : M=512, N=5184, K=256
    gemm_nt_bf16<<<dim3((HW + 127) / 128, CIN / 128, BATCH), 256, 0, stream>>>(
        Wwbf, ctxT, out, CIN, HW, VC, nullptr, bw, 0);
}

// Round 5
// 185.621 us; speedup vs baseline: 2.8283x; 1.0541x over previous
//
#include <hip/hip_runtime.h>
#include <hip/hip_bf16.h>

#define HW    5184
#define WIDTH 72
#define CIN   512
#define KC    256
#define VC    256
#define NS    110
#define NSP   112   // padded s for QK^T (7*16)
#define SPV   128   // padded s for PV k-dim (4*32)
#define BATCH 8

typedef unsigned short u16;
typedef unsigned int   u32;
typedef __attribute__((ext_vector_type(8))) short bf16x8;   // 8 bf16 = 4 VGPRs
typedef __attribute__((ext_vector_type(4))) float f32x4;

typedef const __attribute__((address_space(1))) u32* gp_t;
typedef __attribute__((address_space(3))) u32* lp_t;

__device__ __forceinline__ u32 f2bf1(float f) {
    u32 u = __float_as_uint(f);
    return (u + 0x7FFFu + ((u >> 16) & 1u)) >> 16;   // RNE
}
__device__ __forceinline__ u32 pack2(float a, float b) {
    return f2bf1(a) | (f2bf1(b) << 16);
}

// ---------------- prep: fold BN into per-channel scale/bias ----------------
__global__ void prep_kernel(const float* __restrict__ bk, const float* __restrict__ gamma,
                            const float* __restrict__ beta, const float* __restrict__ rmean,
                            const float* __restrict__ rvar, float* __restrict__ inv_out,
                            float* __restrict__ bc_out) {
    int i = threadIdx.x;  // 256 threads, one per Kc channel
    float inv = gamma[i] * rsqrtf(rvar[i] + 1e-5f);
    inv_out[i] = inv;
    bc_out[i]  = bk[i] * inv + beta[i] - rmean[i] * inv;
}

// ---------------- convert Wk/Ww/Wv fp32 -> bf16 ----------------
__global__ __launch_bounds__(256) void cvt_w_kernel(
    const float* __restrict__ Wk, const float* __restrict__ Ww, const float* __restrict__ Wv,
    u16* __restrict__ Wkbf, u16* __restrict__ Wwbf, u16* __restrict__ Wvbf)
{
    int j = (blockIdx.x * 256 + threadIdx.x) * 4;   // grid 384 -> 393216 elems
    const float* s; u16* d;
    if (j < KC * CIN)          { s = Wk; d = Wkbf; }
    else if (j < 2 * KC * CIN) { j -= KC * CIN;     s = Ww; d = Wwbf; }
    else                       { j -= 2 * KC * CIN; s = Wv; d = Wvbf; }
    float4 v = *(const float4*)&s[j];
    uint2 u;
    u.x = pack2(v.x, v.y);
    u.y = pack2(v.z, v.w);
    *(uint2*)&d[j] = u;
}

// ---------------- transpose+cvt: in [z][C][5184] f32 -> out [z][5184][C] bf16 ----------------
__global__ __launch_bounds__(256) void transpose_cvt_kernel(
    const float* __restrict__ in, u16* __restrict__ out, int C)
{
    const int z  = blockIdx.z;
    const int n0 = blockIdx.x * 32;   // HW
    const int k0 = blockIdx.y * 32;   // C
    __shared__ float t[32][33];
    const int tx = threadIdx.x & 31, ty = threadIdx.x >> 5;   // ty 0..7
    const float* src = in + ((size_t)z * C + k0) * HW + n0;
#pragma unroll
    for (int i = 0; i < 4; i++)
        t[ty + i * 8][tx] = src[(size_t)(ty + i * 8) * HW + tx];
    __syncthreads();
    u16* dst = out + ((size_t)z * HW + n0) * C + k0;
    const int kp  = (threadIdx.x & 15) * 2;
    const int nl0 = threadIdx.x >> 4;           // 0..15
#pragma unroll
    for (int j = 0; j < 2; j++) {
        int nl = nl0 + j * 16;
        u32 u = pack2(t[kp][nl], t[kp + 1][nl]);
        *(u32*)&dst[(size_t)nl * C + kp] = u;
    }
}

// ---------------- bf16 MFMA NT-GEMM, 2-phase double-buffered pipeline ----------------
// C[z][m][n] = sum_k A[m][k] * B[z][n][k]; optional transposed bf16 out Ct[z][n][m].
// Flattened 1D grid, m-fastest decode + bijective XCD chunking (each XCD owns a
// contiguous logical chunk -> B-panels reused within one XCD L2).
__global__ __launch_bounds__(256) void gemm_nt_bf16(
    const u16* __restrict__ A, const u16* __restrict__ B, float* __restrict__ C,
    u16* __restrict__ Ct,
    int M, int N, int K, int nbx, int nby,
    const float* __restrict__ scale, const float* __restrict__ bias, int relu)
{
    // XCD-bijective swizzle (m204 formula)
    const int tot = nbx * nby * BATCH;
    const int q = tot >> 3, r = tot & 7;
    const int xcd = blockIdx.x & 7;
    const int wg  = (xcd < r ? xcd * (q + 1) : r * (q + 1) + (xcd - r) * q) + (blockIdx.x >> 3);
    const int mb_ = wg % nby;
    const int nb_ = (wg / nby) % nbx;
    const int z   = wg / (nby * nbx);

    const int n0 = nb_ * 128;
    const int m0 = mb_ * 128;
    const size_t boff = (size_t)z * N * K;
    const size_t coff = (size_t)z * M * N;
    const int tid  = threadIdx.x;
    const int wid  = tid >> 6;
    const int lane = tid & 63;

    __shared__ __align__(16) u16 As[2][4][128][8];   // 2 x 8 KB
    __shared__ __align__(16) u16 Bs[2][4][128][8];   // 2 x 8 KB

    const int kg0  = (wid & 1) * 2;
    const int half = (wid >> 1) * 64;

    const u16* gA = A + (size_t)(m0 + half + lane) * K + kg0 * 8;
    int nIdx = n0 + half + lane;
    if (nIdx > N - 1) nIdx = N - 1;               // clamp tail block (dup loads, stores masked)
    const u16* gB = B + boff + (size_t)nIdx * K + kg0 * 8;

    const int wm  = (wid >> 1) * 64;
    const int wn  = (wid & 1) * 64;
    const int l16 = lane & 15;
    const int lq  = lane >> 4;

    f32x4 acc[4][4];
#pragma unroll
    for (int mi = 0; mi < 4; mi++)
#pragma unroll
        for (int ni = 0; ni < 4; ni++)
            acc[mi][ni] = (f32x4){0.f, 0.f, 0.f, 0.f};

#define STAGE(d, kk)                                                                              \
    __builtin_amdgcn_global_load_lds((gp_t)(gA + (kk)),     (lp_t)&As[d][kg0][half][0], 16, 0, 0);\
    __builtin_amdgcn_global_load_lds((gp_t)(gA + (kk) + 8), (lp_t)&As[d][kg0+1][half][0],16, 0, 0);\
    __builtin_amdgcn_global_load_lds((gp_t)(gB + (kk)),     (lp_t)&Bs[d][kg0][half][0], 16, 0, 0);\
    __builtin_amdgcn_global_load_lds((gp_t)(gB + (kk) + 8), (lp_t)&Bs[d][kg0+1][half][0],16, 0, 0);

    const int NT = K >> 5;
    STAGE(0, 0)
    __syncthreads();   // drain prologue staging

    int cur = 0;
    for (int t = 0; t < NT; ++t) {
        if (t + 1 < NT) { STAGE(cur ^ 1, (t + 1) * 32) }   // issue next tile EARLY
        bf16x8 af[4], bf[4];
#pragma unroll
        for (int i = 0; i < 4; i++) {
            af[i] = *(const bf16x8*)&As[cur][lq][wm + i * 16 + l16][0];
            bf[i] = *(const bf16x8*)&Bs[cur][lq][wn + i * 16 + l16][0];
        }
#pragma unroll
        for (int mi = 0; mi < 4; mi++)
#pragma unroll
            for (int ni = 0; ni < 4; ni++)
                acc[mi][ni] = __builtin_amdgcn_mfma_f32_16x16x32_bf16(
                    af[mi], bf[ni], acc[mi][ni], 0, 0, 0);
        __syncthreads();   // one barrier per K-step: drains staging, protects cur buf
        cur ^= 1;
    }
#undef STAGE

#pragma unroll
    for (int mi = 0; mi < 4; mi++) {
        const int mb = m0 + wm + mi * 16 + lq * 4;
        float sc[4], bi[4];
#pragma unroll
        for (int r2 = 0; r2 < 4; r2++) {
            sc[r2] = scale ? scale[mb + r2] : 1.0f;
            bi[r2] = bias  ? bias[mb + r2]  : 0.0f;
        }
#pragma unroll
        for (int ni = 0; ni < 4; ni++) {
            const int n = n0 + wn + ni * 16 + l16;
            if (n < N) {
                float v[4];
#pragma unroll
                for (int r2 = 0; r2 < 4; r2++) {
                    v[r2] = acc[mi][ni][r2] * sc[r2] + bi[r2];
                    if (relu) v[r2] = fmaxf(v[r2], 0.f);
                    C[coff + (size_t)(mb + r2) * N + n] = v[r2];
                }
                if (Ct) {   // transposed bf16 write: Ct[z][n][m]
                    uint2 u;
                    u.x = pack2(v[0], v[1]);
                    u.y = pack2(v[2], v[3]);
                    *(uint2*)&Ct[(size_t)z * N * M + (size_t)n * M + mb] = u;
                }
            }
        }
    }
}

// ---------------- value MFMA GEMM: valT (SWIZZLED) [b][v][s] bf16 ----------------
// A = Wvbf [256][512], B = pxb [b][128][512] (pad rows zeroed)
// Write layout: within-batch byte = v*256 + ((s*2) ^ ((v&7)<<4))  [matches attn LDS reads]
__global__ __launch_bounds__(256) void value_mfma_kernel(
    const u16* __restrict__ A, const u16* __restrict__ Bp,
    const float* __restrict__ bv, u16* __restrict__ valT)
{
    const int m0 = blockIdx.x * 128;              // v-block (0 or 128)
    const int b  = blockIdx.y;
    const int tid  = threadIdx.x;
    const int wid  = tid >> 6;
    const int lane = tid & 63;

    __shared__ __align__(16) u16 As[4][128][8];
    __shared__ __align__(16) u16 Bs[4][128][8];

    const int kg0  = (wid & 1) * 2;
    const int half = (wid >> 1) * 64;

    const u16* gA = A + (size_t)(m0 + half + lane) * CIN + kg0 * 8;
    const u16* gB = Bp + (size_t)b * SPV * CIN + (size_t)(half + lane) * CIN + kg0 * 8;

    lp_t lA0 = (lp_t)&As[kg0][half][0];
    lp_t lA1 = (lp_t)&As[kg0 + 1][half][0];
    lp_t lB0 = (lp_t)&Bs[kg0][half][0];
    lp_t lB1 = (lp_t)&Bs[kg0 + 1][half][0];

    const int wm  = (wid >> 1) * 64;
    const int wn  = (wid & 1) * 64;
    const int l16 = lane & 15;
    const int lq  = lane >> 4;

    f32x4 acc[4][4];
#pragma unroll
    for (int mi = 0; mi < 4; mi++)
#pragma unroll
        for (int ni = 0; ni < 4; ni++)
            acc[mi][ni] = (f32x4){0.f, 0.f, 0.f, 0.f};

    for (int k0 = 0; k0 < CIN; k0 += 32) {
        __builtin_amdgcn_global_load_lds((gp_t)(gA + k0),     lA0, 16, 0, 0);
        __builtin_amdgcn_global_load_lds((gp_t)(gA + k0 + 8), lA1, 16, 0, 0);
        __builtin_amdgcn_global_load_lds((gp_t)(gB + k0),     lB0, 16, 0, 0);
        __builtin_amdgcn_global_load_lds((gp_t)(gB + k0 + 8), lB1, 16, 0, 0);
        __syncthreads();

        bf16x8 af[4], bf[4];
#pragma unroll
        for (int i = 0; i < 4; i++) {
            af[i] = *(const bf16x8*)&As[lq][wm + i * 16 + l16][0];
            bf[i] = *(const bf16x8*)&Bs[lq][wn + i * 16 + l16][0];
        }
#pragma unroll
        for (int mi = 0; mi < 4; mi++)
#pragma unroll
            for (int ni = 0; ni < 4; ni++)
                acc[mi][ni] = __builtin_amdgcn_mfma_f32_16x16x32_bf16(
                    af[mi], bf[ni], acc[mi][ni], 0, 0, 0);
        __syncthreads();
    }

    char* vb = (char*)valT + (size_t)b * VC * SPV * 2;
#pragma unroll
    for (int mi = 0; mi < 4; mi++) {
        const int mb = m0 + wm + mi * 16 + lq * 4;
        float bi[4];
#pragma unroll
        for (int r = 0; r < 4; r++) bi[r] = bv[mb + r];
#pragma unroll
        for (int ni = 0; ni < 4; ni++) {
            const int n = wn + ni * 16 + l16;   // s index, 0..127
#pragma unroll
            for (int r = 0; r < 4; r++) {
                const int v = mb + r;
                const int byte = v * 256 + ((n * 2) ^ ((v & 7) << 4));
                *(u16*)(vb + byte) = (u16)f2bf1(acc[mi][ni][r] + bi[r]);
            }
        }
    }
}

// ---------------- PSP pooling px: x [b][512][5184] f32 -> pxb [b][128][512] bf16 ----------------
__global__ __launch_bounds__(128) void psp_pool_px_kernel(
    const float* __restrict__ in, u16* __restrict__ out)
{
    const int c = blockIdx.x;   // 0..511
    const int b = blockIdx.y;
    const int t = threadIdx.x;
    __shared__ float4 row4[1296];
    __shared__ float aux[100];
    float* row = (float*)row4;
    const float* src = in + ((size_t)b * CIN + c) * HW;
    for (int idx = t; idx < 1296; idx += 128)
        row4[idx] = *(const float4*)(src + idx * 4);
    __syncthreads();
    if (t < 64) {
        int r0 = (t >> 3) * 9, c0 = (t & 7) * 9;
        float s = 0.f;
        for (int i = 0; i < 9; i++)
            for (int j = 0; j < 9; j++) s += row[(r0 + i) * WIDTH + c0 + j];
        aux[t] = s;
    } else if (t < 100) {
        int tt = t - 64;
        int r0 = (tt / 6) * 12, c0 = (tt % 6) * 12;
        float s = 0.f;
        for (int i = 0; i < 12; i++)
            for (int j = 0; j < 12; j++) s += row[(r0 + i) * WIDTH + c0 + j];
        aux[64 + tt] = s;
    }
    __syncthreads();
    u16* ob = out + (size_t)b * SPV * CIN + c;
    if (t < 64) ob[(size_t)(46 + t) * CIN] = (u16)f2bf1(aux[t] * (1.f / 81.f));
    if (t < 36) ob[(size_t)(10 + t) * CIN] = (u16)f2bf1(aux[64 + t] * (1.f / 144.f));
    if (t < 9) {
        int r = t / 3, cc = t % 3;
        float s4 = aux[64 + (2 * r) * 6 + 2 * cc] + aux[64 + (2 * r) * 6 + 2 * cc + 1]
                 + aux[64 + (2 * r + 1) * 6 + 2 * cc] + aux[64 + (2 * r + 1) * 6 + 2 * cc + 1];
        ob[(size_t)(1 + t) * CIN] = (u16)f2bf1(s4 * (1.f / 576.f));
    }
    if (t == 0) {
        float s = 0.f;
        for (int i = 0; i < 64; i++) s += aux[i];
        ob[0] = (u16)f2bf1(s * (1.f / 5184.f));
    }
    if (t < 18) ob[(size_t)(110 + t) * CIN] = 0;   // zero pad rows (NaN safety for value GEMM)
}

// ---------------- PSP pooling bf16 (SWIZZLED): k [b][256][5184] -> keyt [b][112][256] ----------------
// Write layout: within-batch byte = s*512 + ((c*2) ^ ((s&7)<<4))  [matches attn LDS reads]
__global__ __launch_bounds__(128) void psp_pool_bf16_kernel(
    const float* __restrict__ in, u16* __restrict__ out)
{
    const int c = blockIdx.x;   // 0..255
    const int b = blockIdx.y;
    const int t = threadIdx.x;
    __shared__ float4 row4[1296];
    __shared__ float aux[100];
    float* row = (float*)row4;
    const float* src = in + ((size_t)b * KC + c) * HW;
    for (int idx = t; idx < 1296; idx += 128)
        row4[idx] = *(const float4*)(src + idx * 4);
    __syncthreads();
    if (t < 64) {
        int r0 = (t >> 3) * 9, c0 = (t & 7) * 9;
        float s = 0.f;
        for (int i = 0; i < 9; i++)
            for (int j = 0; j < 9; j++) s += row[(r0 + i) * WIDTH + c0 + j];
        aux[t] = s;
    } else if (t < 100) {
        int tt = t - 64;
        int r0 = (tt / 6) * 12, c0 = (tt % 6) * 12;
        float s = 0.f;
        for (int i = 0; i < 12; i++)
            for (int j = 0; j < 12; j++) s += row[(r0 + i) * WIDTH + c0 + j];
        aux[64 + tt] = s;
    }
    __syncthreads();
    char* ob = (char*)out + (size_t)b * NSP * KC * 2;
    const int c2 = c * 2;
#define KWR(S, V) *(u16*)(ob + (S) * 512 + (c2 ^ (((S) & 7) << 4))) = (u16)f2bf1(V)
    if (t < 64) KWR(46 + t, aux[t] * (1.f / 81.f));
    if (t < 36) KWR(10 + t, aux[64 + t] * (1.f / 144.f));
    if (t < 9) {
        int r = t / 3, cc = t % 3;
        float s4 = aux[64 + (2 * r) * 6 + 2 * cc] + aux[64 + (2 * r) * 6 + 2 * cc + 1]
                 + aux[64 + (2 * r + 1) * 6 + 2 * cc] + aux[64 + (2 * r + 1) * 6 + 2 * cc + 1];
        KWR(1 + t, s4 * (1.f / 576.f));
    }
    if (t == 0) {
        float s = 0.f;
        for (int i = 0; i < 64; i++) s += aux[i];
        KWR(0, s * (1.f / 5184.f));
        KWR(110, 0.f);   // zero pad rows
        KWR(111, 0.f);
    }
#undef KWR
}

// ---------------- MFMA attention: 64 px/block, 4 waves x 16 px; K/V LDS-staged ----------------
// qT: [b][5184][256] bf16 (linear), keyt: [b][112][256] bf16 SWIZZLED,
// valT: [b][256][128] bf16 SWIZZLED, ctxT out: [b][5184][256] bf16 (linear)
__global__ __launch_bounds__(256) void attn_mfma_kernel(
    const u16* __restrict__ qT, const u16* __restrict__ keyt,
    const u16* __restrict__ valT, u16* __restrict__ ctxT)
{
    const int b    = blockIdx.y;
    const int tid  = threadIdx.x;
    const int wid  = tid >> 6;
    const int lane = tid & 63;
    const int l16  = lane & 15;
    const int lq   = lane >> 4;
    const int px0  = blockIdx.x * 64 + wid * 16;   // wave's 16-px row base

    // LDS: K (swizzled rows of 512B) at byte 0..57343; V (swizzled rows of 256B) at 57344..122879.
    // P [64][256B] overlays the K region after QK^T (barrier-protected).
    __shared__ __align__(16) u16 SM[61440];        // 122880 B -> 1 block/CU
    char* base = (char*)SM;
    const int VOFF = 57344;

    // ---- stage K and V (linear copy; global layout already swizzled) ----
    {
        const char* gk = (const char*)keyt + (size_t)b * (NSP * KC * 2);
        const char* gv = (const char*)valT + (size_t)b * (VC * SPV * 2);
#pragma unroll
        for (int i = 0; i < 14; i++) {             // K: 56 KiB = 4 waves x 14 x 1 KiB
            const int o = (wid * 14 + i) * 1024;
            __builtin_amdgcn_global_load_lds((gp_t)(gk + o + lane * 16), (lp_t)(base + o), 16, 0, 0);
        }
#pragma unroll
        for (int i = 0; i < 16; i++) {             // V: 64 KiB = 4 waves x 16 x 1 KiB
            const int o = (wid * 16 + i) * 1024;
            __builtin_amdgcn_global_load_lds((gp_t)(gv + o + lane * 16), (lp_t)(base + VOFF + o), 16, 0, 0);
        }
    }

    // ---- preload all 8 q fragments (overlaps with staging drain) ----
    const u16* qrow = qT + ((size_t)b * HW + px0 + l16) * KC + lq * 8;
    bf16x8 aq[8];
#pragma unroll
    for (int ks = 0; ks < 8; ks++) aq[ks] = *(const bf16x8*)(qrow + ks * 32);

    __syncthreads();   // staging complete (vmcnt drained at barrier)

    // ==== QK^T from LDS: acc[ni] rows px 4*lq+r, cols s ni*16+l16 ====
    f32x4 acc[7];
#pragma unroll
    for (int ni = 0; ni < 7; ni++) acc[ni] = (f32x4){0.f, 0.f, 0.f, 0.f};
#pragma unroll
    for (int ks = 0; ks < 8; ks++) {
#pragma unroll
        for (int ni = 0; ni < 7; ni++) {
            const int s = ni * 16 + l16;
            const int byte = s * 512 + ((ks * 64 + lq * 16) ^ ((s & 7) << 4));
            bf16x8 bk = *(const bf16x8*)(base + byte);
            acc[ni] = __builtin_amdgcn_mfma_f32_16x16x32_bf16(aq[ks], bk, acc[ni], 0, 0, 0);
        }
    }

    // mask pad columns s=110,111 (ni=6, l16>=14)
    if (l16 >= 14) acc[6] = (f32x4){-1e30f, -1e30f, -1e30f, -1e30f};

    // ==== softmax over s (in-register) ====
    float mx[4], sm[4], rn[4];
#pragma unroll
    for (int r = 0; r < 4; r++) {
        float m = acc[0][r];
#pragma unroll
        for (int ni = 1; ni < 7; ni++) m = fmaxf(m, acc[ni][r]);
        m = fmaxf(m, __shfl_xor(m, 1));
        m = fmaxf(m, __shfl_xor(m, 2));
        m = fmaxf(m, __shfl_xor(m, 4));
        m = fmaxf(m, __shfl_xor(m, 8));
        mx[r] = m * 0.0625f;     // fold Kc^-0.5
        sm[r] = 0.f;
    }

    __syncthreads();   // ALL waves done reading K -> safe to overlay P on K region

    const int prow = wid * 16 + 4 * lq;
#pragma unroll
    for (int ni = 0; ni < 7; ni++) {
#pragma unroll
        for (int r = 0; r < 4; r++) {
            float p = __expf(acc[ni][r] * 0.0625f - mx[r]);   // masked cols -> 0
            sm[r] += p;
            const int row = prow + r;
            const int byte = row * 256 + (((ni * 16 + l16) * 2) ^ ((row & 7) << 4));
            *(u16*)(base + byte) = (u16)f2bf1(p);
        }
    }
    // zero pad cols 112..127 (2 x 16B per row)
    if (l16 < 2) {
#pragma unroll
        for (int r = 0; r < 4; r++) {
            const int row = prow + r;
            const int byte = row * 256 + ((224 + l16 * 16) ^ ((row & 7) << 4));
            *(bf16x8*)(base + byte) = (bf16x8){0, 0, 0, 0, 0, 0, 0, 0};
        }
    }
#pragma unroll
    for (int r = 0; r < 4; r++) {
        float s = sm[r];
        s += __shfl_xor(s, 1);
        s += __shfl_xor(s, 2);
        s += __shfl_xor(s, 4);
        s += __shfl_xor(s, 8);
        rn[r] = 1.f / s;
    }

    __syncthreads();   // P visible

    // ==== PV from LDS: ctx[px][v] = sum_s P[px][s] * V[v][s] ====
    f32x4 acc2[16];
#pragma unroll
    for (int ni = 0; ni < 16; ni++) acc2[ni] = (f32x4){0.f, 0.f, 0.f, 0.f};
    const int arow = wid * 16 + l16;
    const int aswz = (arow & 7) << 4;
#pragma unroll
    for (int ks = 0; ks < 4; ks++) {
        const int pbyte = arow * 256 + ((ks * 64 + lq * 16) ^ aswz);
        bf16x8 pa = *(const bf16x8*)(base + pbyte);
#pragma unroll
        for (int ni = 0; ni < 16; ni++) {
            const int v = ni * 16 + l16;
            const int vbyte = VOFF + v * 256 + ((ks * 64 + lq * 16) ^ ((v & 7) << 4));
            bf16x8 bvv = *(const bf16x8*)(base + vbyte);
            acc2[ni] = __builtin_amdgcn_mfma_f32_16x16x32_bf16(pa, bvv, acc2[ni], 0, 0, 0);
        }
    }

    // epilogue: normalize by row sum, write ctxT[b][px][v] bf16
    u16* crow = ctxT + ((size_t)b * HW + px0 + 4 * lq) * VC + l16;
#pragma unroll
    for (int ni = 0; ni < 16; ni++) {
#pragma unroll
        for (int r = 0; r < 4; r++) {
            float v = acc2[ni][r] * rn[r];
            crow[(size_t)r * VC + ni * 16] = (u16)f2bf1(v);
        }
    }
}

extern "C" void kernel_launch(void* const* d_in, const int* in_sizes, int n_in,
                              void* d_out, int out_size, void* d_ws, size_t ws_size,
                              hipStream_t stream)
{
    const float* x     = (const float*)d_in[0];
    const float* Wk    = (const float*)d_in[1];
    const float* bk    = (const float*)d_in[2];
    const float* gamma = (const float*)d_in[3];
    const float* beta  = (const float*)d_in[4];
    const float* rmean = (const float*)d_in[5];
    const float* rvar  = (const float*)d_in[6];
    const float* Wv    = (const float*)d_in[7];
    const float* bv    = (const float*)d_in[8];
    const float* Ww    = (const float*)d_in[9];
    const float* bw    = (const float*)d_in[10];
    float* out = (float*)d_out;

    float* ws    = (float*)d_ws;
    float* k_ws  = ws;                                        // [8][256][5184] f32
    u16*   xT    = (u16*)(k_ws + (size_t)BATCH * KC * HW);    // [8][5184][512] bf16 (dead after gemm1)
    u16*   ctxT  = xT;                                        // alias: [8][5184][256] bf16 (attn runs after gemm1)
    u16*   kT    = xT + (size_t)BATCH * HW * CIN;             // [8][5184][256] bf16 (FRESH - gemm1 writes it while reading xT)
    u16*   pxb   = kT + (size_t)BATCH * HW * KC;              // [8][128][512] bf16
    u16*   keytb = pxb + (size_t)BATCH * SPV * CIN;           // [8][112][256] bf16 (swizzled)
    u16*   valT  = keytb + (size_t)BATCH * NSP * KC;          // [8][256][128] bf16 (swizzled)
    u16*   Wkbf  = valT + (size_t)BATCH * VC * SPV;           // [256][512] bf16
    u16*   Wwbf  = Wkbf + (size_t)KC * CIN;                   // [512][256] bf16
    u16*   Wvbf  = Wwbf + (size_t)CIN * VC;                   // [256][512] bf16
    float* inv   = (float*)(Wvbf + (size_t)KC * CIN);         // [256]
    float* bc    = inv + 256;                                 // [256]

    prep_kernel<<<1, 256, 0, stream>>>(bk, gamma, beta, rmean, rvar, inv, bc);
    cvt_w_kernel<<<384, 256, 0, stream>>>(Wk, Ww, Wv, Wkbf, Wwbf, Wvbf);
    psp_pool_px_kernel<<<dim3(CIN, BATCH), 128, 0, stream>>>(x, pxb);
    transpose_cvt_kernel<<<dim3(HW / 32, CIN / 32, BATCH), 256, 0, stream>>>(x, xT, CIN);
    // k = relu(BN(Wk @ x)) : M=256, N=5184, K=512; fp32 k_ws (for psp) + bf16 kT (for attn)
    {
        const int nbx = (HW + 127) / 128, nby = KC / 128;
        gemm_nt_bf16<<<nbx * nby * BATCH, 256, 0, stream>>>(
            Wkbf, xT, k_ws, kT, KC, HW, CIN, nbx, nby, inv, bc, 1);
    }
    psp_pool_bf16_kernel<<<dim3(KC, BATCH), 128, 0, stream>>>(k_ws, keytb);
    value_mfma_kernel<<<dim3(2, BATCH), 256, 0, stream>>>(Wvbf, pxb, bv, valT);
    attn_mfma_kernel<<<dim3(HW / 64, BATCH), 256, 0, stream>>>(kT, keytb, valT, ctxT);
    // out = Ww @ ctx + bw : M=512, N=5184, K=256
    {
        const int nbx = (HW + 127) / 128, nby = CIN / 128;
        gemm_nt_bf16<<<nbx * nby * BATCH, 256, 0, stream>>>(
            Wwbf, ctxT, out, nullptr, CIN, HW, VC, nbx, nby, nullptr, bw, 0);
    }
}

// Round 6
// 184.392 us; speedup vs baseline: 2.8471x; 1.0067x over previous
//
#include <hip/hip_runtime.h>
#include <hip/hip_bf16.h>

#define HW    5184
#define WIDTH 72
#define CIN   512
#define KC    256
#define VC    256
#define NS    110
#define NSP   112   // padded s for QK^T (7*16)
#define SPV   128   // padded s for PV k-dim (4*32)
#define BATCH 8

typedef unsigned short u16;
typedef unsigned int   u32;
typedef __attribute__((ext_vector_type(8))) short bf16x8;   // 8 bf16 = 4 VGPRs
typedef __attribute__((ext_vector_type(4))) float f32x4;

typedef const __attribute__((address_space(1))) u32* gp_t;
typedef __attribute__((address_space(3))) u32* lp_t;

__device__ __forceinline__ u32 f2bf1(float f) {
    u32 u = __float_as_uint(f);
    return (u + 0x7FFFu + ((u >> 16) & 1u)) >> 16;   // RNE
}
__device__ __forceinline__ u32 pack2(float a, float b) {
    return f2bf1(a) | (f2bf1(b) << 16);
}

// ---------------- prep: fold BN into per-channel scale/bias ----------------
__global__ void prep_kernel(const float* __restrict__ bk, const float* __restrict__ gamma,
                            const float* __restrict__ beta, const float* __restrict__ rmean,
                            const float* __restrict__ rvar, float* __restrict__ inv_out,
                            float* __restrict__ bc_out) {
    int i = threadIdx.x;  // 256 threads, one per Kc channel
    float inv = gamma[i] * rsqrtf(rvar[i] + 1e-5f);
    inv_out[i] = inv;
    bc_out[i]  = bk[i] * inv + beta[i] - rmean[i] * inv;
}

// ---------------- convert Wk/Ww/Wv fp32 -> bf16 ----------------
__global__ __launch_bounds__(256) void cvt_w_kernel(
    const float* __restrict__ Wk, const float* __restrict__ Ww, const float* __restrict__ Wv,
    u16* __restrict__ Wkbf, u16* __restrict__ Wwbf, u16* __restrict__ Wvbf)
{
    int j = (blockIdx.x * 256 + threadIdx.x) * 4;   // grid 384 -> 393216 elems
    const float* s; u16* d;
    if (j < KC * CIN)          { s = Wk; d = Wkbf; }
    else if (j < 2 * KC * CIN) { j -= KC * CIN;     s = Ww; d = Wwbf; }
    else                       { j -= 2 * KC * CIN; s = Wv; d = Wvbf; }
    float4 v = *(const float4*)&s[j];
    uint2 u;
    u.x = pack2(v.x, v.y);
    u.y = pack2(v.z, v.w);
    *(uint2*)&d[j] = u;
}

// ---------------- transpose+cvt: in [z][C][5184] f32 -> out [z][5184][C] bf16 ----------------
__global__ __launch_bounds__(256) void transpose_cvt_kernel(
    const float* __restrict__ in, u16* __restrict__ out, int C)
{
    const int z  = blockIdx.z;
    const int n0 = blockIdx.x * 32;   // HW
    const int k0 = blockIdx.y * 32;   // C
    __shared__ float t[32][33];
    const int tx = threadIdx.x & 31, ty = threadIdx.x >> 5;   // ty 0..7
    const float* src = in + ((size_t)z * C + k0) * HW + n0;
#pragma unroll
    for (int i = 0; i < 4; i++)
        t[ty + i * 8][tx] = src[(size_t)(ty + i * 8) * HW + tx];
    __syncthreads();
    u16* dst = out + ((size_t)z * HW + n0) * C + k0;
    const int kp  = (threadIdx.x & 15) * 2;
    const int nl0 = threadIdx.x >> 4;           // 0..15
#pragma unroll
    for (int j = 0; j < 2; j++) {
        int nl = nl0 + j * 16;
        u32 u = pack2(t[kp][nl], t[kp + 1][nl]);
        *(u32*)&dst[(size_t)nl * C + kp] = u;
    }
}

// ---------------- bf16 MFMA NT-GEMM, counted-vmcnt 3-buffer pipeline ----------------
// C[z][m][n] = sum_k A[m][k] * B[z][n][k]; optional transposed bf16 out Ct[z][n][m].
// Raw s_barrier + s_waitcnt vmcnt(4): never drains the load queue in the main loop
// (each wave issues exactly 4 global_load_lds per K-tile; vmcnt(4) == "my tile-t
// loads landed, tile-t+1 may stay in flight"). 3 LDS buffers: compute(t) reads
// buf[t%3], tile t+1 in flight into buf[(t+1)%3], stage(t+2) -> buf[(t+2)%3]
// (last read at t-1, protected by this iteration's barrier).
__global__ __launch_bounds__(256) void gemm_nt_bf16(
    const u16* __restrict__ A, const u16* __restrict__ B, float* __restrict__ C,
    u16* __restrict__ Ct,
    int M, int N, int K, int nbx, int nby,
    const float* __restrict__ scale, const float* __restrict__ bias, int relu)
{
    // XCD-bijective swizzle (m204 formula), m-fastest decode
    const int tot = nbx * nby * BATCH;
    const int q = tot >> 3, r = tot & 7;
    const int xcd = blockIdx.x & 7;
    const int wg  = (xcd < r ? xcd * (q + 1) : r * (q + 1) + (xcd - r) * q) + (blockIdx.x >> 3);
    const int mb_ = wg % nby;
    const int nb_ = (wg / nby) % nbx;
    const int z   = wg / (nby * nbx);

    const int n0 = nb_ * 128;
    const int m0 = mb_ * 128;
    const size_t boff = (size_t)z * N * K;
    const size_t coff = (size_t)z * M * N;
    const int tid  = threadIdx.x;
    const int wid  = tid >> 6;
    const int lane = tid & 63;

    __shared__ __align__(16) u16 As[3][4][128][8];   // 3 x 8 KB
    __shared__ __align__(16) u16 Bs[3][4][128][8];   // 3 x 8 KB

    const int kg0  = (wid & 1) * 2;
    const int half = (wid >> 1) * 64;

    const u16* gA = A + (size_t)(m0 + half + lane) * K + kg0 * 8;
    int nIdx = n0 + half + lane;
    if (nIdx > N - 1) nIdx = N - 1;               // clamp tail block (dup loads, stores masked)
    const u16* gB = B + boff + (size_t)nIdx * K + kg0 * 8;

    const int wm  = (wid >> 1) * 64;
    const int wn  = (wid & 1) * 64;
    const int l16 = lane & 15;
    const int lq  = lane >> 4;

    f32x4 acc[4][4];
#pragma unroll
    for (int mi = 0; mi < 4; mi++)
#pragma unroll
        for (int ni = 0; ni < 4; ni++)
            acc[mi][ni] = (f32x4){0.f, 0.f, 0.f, 0.f};

#define STAGE(d, kk)                                                                              \
    __builtin_amdgcn_global_load_lds((gp_t)(gA + (kk)),     (lp_t)&As[d][kg0][half][0], 16, 0, 0);\
    __builtin_amdgcn_global_load_lds((gp_t)(gA + (kk) + 8), (lp_t)&As[d][kg0+1][half][0],16, 0, 0);\
    __builtin_amdgcn_global_load_lds((gp_t)(gB + (kk)),     (lp_t)&Bs[d][kg0][half][0], 16, 0, 0);\
    __builtin_amdgcn_global_load_lds((gp_t)(gB + (kk) + 8), (lp_t)&Bs[d][kg0+1][half][0],16, 0, 0);

    const int NT = K >> 5;
    STAGE(0, 0)
    STAGE(1, 32)

    int cur = 0;
    for (int t = 0; t < NT; ++t) {
        // counted wait: my 4 oldest (tile t) landed; tile t+1 may stay in flight
        if (t + 1 < NT) { asm volatile("s_waitcnt vmcnt(4)" ::: "memory"); }
        else            { asm volatile("s_waitcnt vmcnt(0)" ::: "memory"); }
        __builtin_amdgcn_s_barrier();
        __builtin_amdgcn_sched_barrier(0);   // pin: no ds_read / stage hoisted above

        if (t + 2 < NT) {
            int nb = cur + 2; if (nb >= 3) nb -= 3;
            STAGE(nb, (t + 2) * 32)
        }

        bf16x8 af[4], bf[4];
#pragma unroll
        for (int i = 0; i < 4; i++) {
            af[i] = *(const bf16x8*)&As[cur][lq][wm + i * 16 + l16][0];
            bf[i] = *(const bf16x8*)&Bs[cur][lq][wn + i * 16 + l16][0];
        }
        __builtin_amdgcn_s_setprio(1);
#pragma unroll
        for (int mi = 0; mi < 4; mi++)
#pragma unroll
            for (int ni = 0; ni < 4; ni++)
                acc[mi][ni] = __builtin_amdgcn_mfma_f32_16x16x32_bf16(
                    af[mi], bf[ni], acc[mi][ni], 0, 0, 0);
        __builtin_amdgcn_s_setprio(0);

        cur = (cur == 2) ? 0 : cur + 1;
    }
#undef STAGE

#pragma unroll
    for (int mi = 0; mi < 4; mi++) {
        const int mb = m0 + wm + mi * 16 + lq * 4;
        float sc[4], bi[4];
#pragma unroll
        for (int r2 = 0; r2 < 4; r2++) {
            sc[r2] = scale ? scale[mb + r2] : 1.0f;
            bi[r2] = bias  ? bias[mb + r2]  : 0.0f;
        }
#pragma unroll
        for (int ni = 0; ni < 4; ni++) {
            const int n = n0 + wn + ni * 16 + l16;
            if (n < N) {
                float v[4];
#pragma unroll
                for (int r2 = 0; r2 < 4; r2++) {
                    v[r2] = acc[mi][ni][r2] * sc[r2] + bi[r2];
                    if (relu) v[r2] = fmaxf(v[r2], 0.f);
                    C[coff + (size_t)(mb + r2) * N + n] = v[r2];
                }
                if (Ct) {   // transposed bf16 write: Ct[z][n][m]
                    uint2 u;
                    u.x = pack2(v[0], v[1]);
                    u.y = pack2(v[2], v[3]);
                    *(uint2*)&Ct[(size_t)z * N * M + (size_t)n * M + mb] = u;
                }
            }
        }
    }
}

// ---------------- value MFMA GEMM: valT (SWIZZLED) [b][v][s] bf16 ----------------
// A = Wvbf [256][512], B = pxb [b][128][512] (pad rows zeroed)
// Write layout: within-batch byte = v*256 + ((s*2) ^ ((v&7)<<4))  [matches attn LDS reads]
__global__ __launch_bounds__(256) void value_mfma_kernel(
    const u16* __restrict__ A, const u16* __restrict__ Bp,
    const float* __restrict__ bv, u16* __restrict__ valT)
{
    const int m0 = blockIdx.x * 128;              // v-block (0 or 128)
    const int b  = blockIdx.y;
    const int tid  = threadIdx.x;
    const int wid  = tid >> 6;
    const int lane = tid & 63;

    __shared__ __align__(16) u16 As[4][128][8];
    __shared__ __align__(16) u16 Bs[4][128][8];

    const int kg0  = (wid & 1) * 2;
    const int half = (wid >> 1) * 64;

    const u16* gA = A + (size_t)(m0 + half + lane) * CIN + kg0 * 8;
    const u16* gB = Bp + (size_t)b * SPV * CIN + (size_t)(half + lane) * CIN + kg0 * 8;

    lp_t lA0 = (lp_t)&As[kg0][half][0];
    lp_t lA1 = (lp_t)&As[kg0 + 1][half][0];
    lp_t lB0 = (lp_t)&Bs[kg0][half][0];
    lp_t lB1 = (lp_t)&Bs[kg0 + 1][half][0];

    const int wm  = (wid >> 1) * 64;
    const int wn  = (wid & 1) * 64;
    const int l16 = lane & 15;
    const int lq  = lane >> 4;

    f32x4 acc[4][4];
#pragma unroll
    for (int mi = 0; mi < 4; mi++)
#pragma unroll
        for (int ni = 0; ni < 4; ni++)
            acc[mi][ni] = (f32x4){0.f, 0.f, 0.f, 0.f};

    for (int k0 = 0; k0 < CIN; k0 += 32) {
        __builtin_amdgcn_global_load_lds((gp_t)(gA + k0),     lA0, 16, 0, 0);
        __builtin_amdgcn_global_load_lds((gp_t)(gA + k0 + 8), lA1, 16, 0, 0);
        __builtin_amdgcn_global_load_lds((gp_t)(gB + k0),     lB0, 16, 0, 0);
        __builtin_amdgcn_global_load_lds((gp_t)(gB + k0 + 8), lB1, 16, 0, 0);
        __syncthreads();

        bf16x8 af[4], bf[4];
#pragma unroll
        for (int i = 0; i < 4; i++) {
            af[i] = *(const bf16x8*)&As[lq][wm + i * 16 + l16][0];
            bf[i] = *(const bf16x8*)&Bs[lq][wn + i * 16 + l16][0];
        }
#pragma unroll
        for (int mi = 0; mi < 4; mi++)
#pragma unroll
            for (int ni = 0; ni < 4; ni++)
                acc[mi][ni] = __builtin_amdgcn_mfma_f32_16x16x32_bf16(
                    af[mi], bf[ni], acc[mi][ni], 0, 0, 0);
        __syncthreads();
    }

    char* vb = (char*)valT + (size_t)b * VC * SPV * 2;
#pragma unroll
    for (int mi = 0; mi < 4; mi++) {
        const int mb = m0 + wm + mi * 16 + lq * 4;
        float bi[4];
#pragma unroll
        for (int r = 0; r < 4; r++) bi[r] = bv[mb + r];
#pragma unroll
        for (int ni = 0; ni < 4; ni++) {
            const int n = wn + ni * 16 + l16;   // s index, 0..127
#pragma unroll
            for (int r = 0; r < 4; r++) {
                const int v = mb + r;
                const int byte = v * 256 + ((n * 2) ^ ((v & 7) << 4));
                *(u16*)(vb + byte) = (u16)f2bf1(acc[mi][ni][r] + bi[r]);
            }
        }
    }
}

// ---------------- PSP pooling px: x [b][512][5184] f32 -> pxb [b][128][512] bf16 ----------------
__global__ __launch_bounds__(128) void psp_pool_px_kernel(
    const float* __restrict__ in, u16* __restrict__ out)
{
    const int c = blockIdx.x;   // 0..511
    const int b = blockIdx.y;
    const int t = threadIdx.x;
    __shared__ float4 row4[1296];
    __shared__ float aux[100];
    float* row = (float*)row4;
    const float* src = in + ((size_t)b * CIN + c) * HW;
    for (int idx = t; idx < 1296; idx += 128)
        row4[idx] = *(const float4*)(src + idx * 4);
    __syncthreads();
    if (t < 64) {
        int r0 = (t >> 3) * 9, c0 = (t & 7) * 9;
        float s = 0.f;
        for (int i = 0; i < 9; i++)
            for (int j = 0; j < 9; j++) s += row[(r0 + i) * WIDTH + c0 + j];
        aux[t] = s;
    } else if (t < 100) {
        int tt = t - 64;
        int r0 = (tt / 6) * 12, c0 = (tt % 6) * 12;
        float s = 0.f;
        for (int i = 0; i < 12; i++)
            for (int j = 0; j < 12; j++) s += row[(r0 + i) * WIDTH + c0 + j];
        aux[64 + tt] = s;
    }
    __syncthreads();
    u16* ob = out + (size_t)b * SPV * CIN + c;
    if (t < 64) ob[(size_t)(46 + t) * CIN] = (u16)f2bf1(aux[t] * (1.f / 81.f));
    if (t < 36) ob[(size_t)(10 + t) * CIN] = (u16)f2bf1(aux[64 + t] * (1.f / 144.f));
    if (t < 9) {
        int r = t / 3, cc = t % 3;
        float s4 = aux[64 + (2 * r) * 6 + 2 * cc] + aux[64 + (2 * r) * 6 + 2 * cc + 1]
                 + aux[64 + (2 * r + 1) * 6 + 2 * cc] + aux[64 + (2 * r + 1) * 6 + 2 * cc + 1];
        ob[(size_t)(1 + t) * CIN] = (u16)f2bf1(s4 * (1.f / 576.f));
    }
    if (t == 0) {
        float s = 0.f;
        for (int i = 0; i < 64; i++) s += aux[i];
        ob[0] = (u16)f2bf1(s * (1.f / 5184.f));
    }
    if (t < 18) ob[(size_t)(110 + t) * CIN] = 0;   // zero pad rows (NaN safety for value GEMM)
}

// ---------------- PSP pooling bf16 (SWIZZLED): k [b][256][5184] -> keyt [b][112][256] ----------------
// Write layout: within-batch byte = s*512 + ((c*2) ^ ((s&7)<<4))  [matches attn LDS reads]
__global__ __launch_bounds__(128) void psp_pool_bf16_kernel(
    const float* __restrict__ in, u16* __restrict__ out)
{
    const int c = blockIdx.x;   // 0..255
    const int b = blockIdx.y;
    const int t = threadIdx.x;
    __shared__ float4 row4[1296];
    __shared__ float aux[100];
    float* row = (float*)row4;
    const float* src = in + ((size_t)b * KC + c) * HW;
    for (int idx = t; idx < 1296; idx += 128)
        row4[idx] = *(const float4*)(src + idx * 4);
    __syncthreads();
    if (t < 64) {
        int r0 = (t >> 3) * 9, c0 = (t & 7) * 9;
        float s = 0.f;
        for (int i = 0; i < 9; i++)
            for (int j = 0; j < 9; j++) s += row[(r0 + i) * WIDTH + c0 + j];
        aux[t] = s;
    } else if (t < 100) {
        int tt = t - 64;
        int r0 = (tt / 6) * 12, c0 = (tt % 6) * 12;
        float s = 0.f;
        for (int i = 0; i < 12; i++)
            for (int j = 0; j < 12; j++) s += row[(r0 + i) * WIDTH + c0 + j];
        aux[64 + tt] = s;
    }
    __syncthreads();
    char* ob = (char*)out + (size_t)b * NSP * KC * 2;
    const int c2 = c * 2;
#define KWR(S, V) *(u16*)(ob + (S) * 512 + (c2 ^ (((S) & 7) << 4))) = (u16)f2bf1(V)
    if (t < 64) KWR(46 + t, aux[t] * (1.f / 81.f));
    if (t < 36) KWR(10 + t, aux[64 + t] * (1.f / 144.f));
    if (t < 9) {
        int r = t / 3, cc = t % 3;
        float s4 = aux[64 + (2 * r) * 6 + 2 * cc] + aux[64 + (2 * r) * 6 + 2 * cc + 1]
                 + aux[64 + (2 * r + 1) * 6 + 2 * cc] + aux[64 + (2 * r + 1) * 6 + 2 * cc + 1];
        KWR(1 + t, s4 * (1.f / 576.f));
    }
    if (t == 0) {
        float s = 0.f;
        for (int i = 0; i < 64; i++) s += aux[i];
        KWR(0, s * (1.f / 5184.f));
        KWR(110, 0.f);   // zero pad rows
        KWR(111, 0.f);
    }
#undef KWR
}

// ---------------- MFMA attention: 64 px/block, 4 waves x 16 px; K/V LDS-staged ----------------
// qT: [b][5184][256] bf16 (linear), keyt: [b][112][256] bf16 SWIZZLED,
// valT: [b][256][128] bf16 SWIZZLED, ctxT out: [b][5184][256] bf16 (linear)
__global__ __launch_bounds__(256) void attn_mfma_kernel(
    const u16* __restrict__ qT, const u16* __restrict__ keyt,
    const u16* __restrict__ valT, u16* __restrict__ ctxT)
{
    const int b    = blockIdx.y;
    const int tid  = threadIdx.x;
    const int wid  = tid >> 6;
    const int lane = tid & 63;
    const int l16  = lane & 15;
    const int lq   = lane >> 4;
    const int px0  = blockIdx.x * 64 + wid * 16;   // wave's 16-px row base

    // LDS: K (swizzled rows of 512B) at byte 0..57343; V (swizzled rows of 256B) at 57344..122879.
    // P [64][256B] overlays the K region after QK^T (barrier-protected).
    __shared__ __align__(16) u16 SM[61440];        // 122880 B -> 1 block/CU
    char* base = (char*)SM;
    const int VOFF = 57344;

    // ---- stage K and V (linear copy; global layout already swizzled) ----
    {
        const char* gk = (const char*)keyt + (size_t)b * (NSP * KC * 2);
        const char* gv = (const char*)valT + (size_t)b * (VC * SPV * 2);
#pragma unroll
        for (int i = 0; i < 14; i++) {             // K: 56 KiB = 4 waves x 14 x 1 KiB
            const int o = (wid * 14 + i) * 1024;
            __builtin_amdgcn_global_load_lds((gp_t)(gk + o + lane * 16), (lp_t)(base + o), 16, 0, 0);
        }
#pragma unroll
        for (int i = 0; i < 16; i++) {             // V: 64 KiB = 4 waves x 16 x 1 KiB
            const int o = (wid * 16 + i) * 1024;
            __builtin_amdgcn_global_load_lds((gp_t)(gv + o + lane * 16), (lp_t)(base + VOFF + o), 16, 0, 0);
        }
    }

    // ---- preload all 8 q fragments (overlaps with staging drain) ----
    const u16* qrow = qT + ((size_t)b * HW + px0 + l16) * KC + lq * 8;
    bf16x8 aq[8];
#pragma unroll
    for (int ks = 0; ks < 8; ks++) aq[ks] = *(const bf16x8*)(qrow + ks * 32);

    __syncthreads();   // staging complete (vmcnt drained at barrier)

    // ==== QK^T from LDS: acc[ni] rows px 4*lq+r, cols s ni*16+l16 ====
    f32x4 acc[7];
#pragma unroll
    for (int ni = 0; ni < 7; ni++) acc[ni] = (f32x4){0.f, 0.f, 0.f, 0.f};
#pragma unroll
    for (int ks = 0; ks < 8; ks++) {
#pragma unroll
        for (int ni = 0; ni < 7; ni++) {
            const int s = ni * 16 + l16;
            const int byte = s * 512 + ((ks * 64 + lq * 16) ^ ((s & 7) << 4));
            bf16x8 bk = *(const bf16x8*)(base + byte);
            acc[ni] = __builtin_amdgcn_mfma_f32_16x16x32_bf16(aq[ks], bk, acc[ni], 0, 0, 0);
        }
    }

    // mask pad columns s=110,111 (ni=6, l16>=14)
    if (l16 >= 14) acc[6] = (f32x4){-1e30f, -1e30f, -1e30f, -1e30f};

    // ==== softmax over s (in-register) ====
    float mx[4], sm[4], rn[4];
#pragma unroll
    for (int r = 0; r < 4; r++) {
        float m = acc[0][r];
#pragma unroll
        for (int ni = 1; ni < 7; ni++) m = fmaxf(m, acc[ni][r]);
        m = fmaxf(m, __shfl_xor(m, 1));
        m = fmaxf(m, __shfl_xor(m, 2));
        m = fmaxf(m, __shfl_xor(m, 4));
        m = fmaxf(m, __shfl_xor(m, 8));
        mx[r] = m * 0.0625f;     // fold Kc^-0.5
        sm[r] = 0.f;
    }

    __syncthreads();   // ALL waves done reading K -> safe to overlay P on K region

    const int prow = wid * 16 + 4 * lq;
#pragma unroll
    for (int ni = 0; ni < 7; ni++) {
#pragma unroll
        for (int r = 0; r < 4; r++) {
            float p = __expf(acc[ni][r] * 0.0625f - mx[r]);   // masked cols -> 0
            sm[r] += p;
            const int row = prow + r;
            const int byte = row * 256 + (((ni * 16 + l16) * 2) ^ ((row & 7) << 4));
            *(u16*)(base + byte) = (u16)f2bf1(p);
        }
    }
    // zero pad cols 112..127 (2 x 16B per row)
    if (l16 < 2) {
#pragma unroll
        for (int r = 0; r < 4; r++) {
            const int row = prow + r;
            const int byte = row * 256 + ((224 + l16 * 16) ^ ((row & 7) << 4));
            *(bf16x8*)(base + byte) = (bf16x8){0, 0, 0, 0, 0, 0, 0, 0};
        }
    }
#pragma unroll
    for (int r = 0; r < 4; r++) {
        float s = sm[r];
        s += __shfl_xor(s, 1);
        s += __shfl_xor(s, 2);
        s += __shfl_xor(s, 4);
        s += __shfl_xor(s, 8);
        rn[r] = 1.f / s;
    }

    __syncthreads();   // P visible

    // ==== PV from LDS: ctx[px][v] = sum_s P[px][s] * V[v][s] ====
    f32x4 acc2[16];
#pragma unroll
    for (int ni = 0; ni < 16; ni++) acc2[ni] = (f32x4){0.f, 0.f, 0.f, 0.f};
    const int arow = wid * 16 + l16;
    const int aswz = (arow & 7) << 4;
#pragma unroll
    for (int ks = 0; ks < 4; ks++) {
        const int pbyte = arow * 256 + ((ks * 64 + lq * 16) ^ aswz);
        bf16x8 pa = *(const bf16x8*)(base + pbyte);
#pragma unroll
        for (int ni = 0; ni < 16; ni++) {
            const int v = ni * 16 + l16;
            const int vbyte = VOFF + v * 256 + ((ks * 64 + lq * 16) ^ ((v & 7) << 4));
            bf16x8 bvv = *(const bf16x8*)(base + vbyte);
            acc2[ni] = __builtin_amdgcn_mfma_f32_16x16x32_bf16(pa, bvv, acc2[ni], 0, 0, 0);
        }
    }

    // epilogue: normalize by row sum, write ctxT[b][px][v] bf16
    u16* crow = ctxT + ((size_t)b * HW + px0 + 4 * lq) * VC + l16;
#pragma unroll
    for (int ni = 0; ni < 16; ni++) {
#pragma unroll
        for (int r = 0; r < 4; r++) {
            float v = acc2[ni][r] * rn[r];
            crow[(size_t)r * VC + ni * 16] = (u16)f2bf1(v);
        }
    }
}

extern "C" void kernel_launch(void* const* d_in, const int* in_sizes, int n_in,
                              void* d_out, int out_size, void* d_ws, size_t ws_size,
                              hipStream_t stream)
{
    const float* x     = (const float*)d_in[0];
    const float* Wk    = (const float*)d_in[1];
    const float* bk    = (const float*)d_in[2];
    const float* gamma = (const float*)d_in[3];
    const float* beta  = (const float*)d_in[4];
    const float* rmean = (const float*)d_in[5];
    const float* rvar  = (const float*)d_in[6];
    const float* Wv    = (const float*)d_in[7];
    const float* bv    = (const float*)d_in[8];
    const float* Ww    = (const float*)d_in[9];
    const float* bw    = (const float*)d_in[10];
    float* out = (float*)d_out;

    float* ws    = (float*)d_ws;
    float* k_ws  = ws;                                        // [8][256][5184] f32
    u16*   xT    = (u16*)(k_ws + (size_t)BATCH * KC * HW);    // [8][5184][512] bf16 (dead after gemm1)
    u16*   ctxT  = xT;                                        // alias: [8][5184][256] bf16 (attn runs after gemm1)
    u16*   kT    = xT + (size_t)BATCH * HW * CIN;             // [8][5184][256] bf16 (FRESH - gemm1 writes it while reading xT)
    u16*   pxb   = kT + (size_t)BATCH * HW * KC;              // [8][128][512] bf16
    u16*   keytb = pxb + (size_t)BATCH * SPV * CIN;           // [8][112][256] bf16 (swizzled)
    u16*   valT  = keytb + (size_t)BATCH * NSP * KC;          // [8][256][128] bf16 (swizzled)
    u16*   Wkbf  = valT + (size_t)BATCH * VC * SPV;           // [256][512] bf16
    u16*   Wwbf  = Wkbf + (size_t)KC * CIN;                   // [512][256] bf16
    u16*   Wvbf  = Wwbf + (size_t)CIN * VC;                   // [256][512] bf16
    float* inv   = (float*)(Wvbf + (size_t)KC * CIN);         // [256]
    float* bc    = inv + 256;                                 // [256]

    prep_kernel<<<1, 256, 0, stream>>>(bk, gamma, beta, rmean, rvar, inv, bc);
    cvt_w_kernel<<<384, 256, 0, stream>>>(Wk, Ww, Wv, Wkbf, Wwbf, Wvbf);
    psp_pool_px_kernel<<<dim3(CIN, BATCH), 128, 0, stream>>>(x, pxb);
    transpose_cvt_kernel<<<dim3(HW / 32, CIN / 32, BATCH), 256, 0, stream>>>(x, xT, CIN);
    // k = relu(BN(Wk @ x)) : M=256, N=5184, K=512; fp32 k_ws (for psp) + bf16 kT (for attn)
    {
        const int nbx = (HW + 127) / 128, nby = KC / 128;
        gemm_nt_bf16<<<nbx * nby * BATCH, 256, 0, stream>>>(
            Wkbf, xT, k_ws, kT, KC, HW, CIN, nbx, nby, inv, bc, 1);
    }
    psp_pool_bf16_kernel<<<dim3(KC, BATCH), 128, 0, stream>>>(k_ws, keytb);
    value_mfma_kernel<<<dim3(2, BATCH), 256, 0, stream>>>(Wvbf, pxb, bv, valT);
    attn_mfma_kernel<<<dim3(HW / 64, BATCH), 256, 0, stream>>>(kT, keytb, valT, ctxT);
    // out = Ww @ ctx + bw : M=512, N=5184, K=256
    {
        const int nbx = (HW + 127) / 128, nby = CIN / 128;
        gemm_nt_bf16<<<nbx * nby * BATCH, 256, 0, stream>>>(
            Wwbf, ctxT, out, nullptr, CIN, HW, VC, nbx, nby, nullptr, bw, 0);
    }
}

// Round 7
// 178.101 us; speedup vs baseline: 2.9477x; 1.0353x over previous
//
#include <hip/hip_runtime.h>
#include <hip/hip_bf16.h>

#define HW    5184
#define WIDTH 72
#define CIN   512
#define KC    256
#define VC    256
#define NS    110
#define NSP   112   // padded s for QK^T (7*16)
#define SPV   128   // padded s for PV k-dim (4*32)
#define BATCH 8

typedef unsigned short u16;
typedef unsigned int   u32;
typedef __attribute__((ext_vector_type(8))) short bf16x8;   // 8 bf16 = 4 VGPRs
typedef __attribute__((ext_vector_type(4))) float f32x4;

typedef const __attribute__((address_space(1))) u32* gp_t;
typedef __attribute__((address_space(3))) u32* lp_t;

__device__ __forceinline__ u32 f2bf1(float f) {
    u32 u = __float_as_uint(f);
    return (u + 0x7FFFu + ((u >> 16) & 1u)) >> 16;   // RNE
}
__device__ __forceinline__ u32 pack2(float a, float b) {
    return f2bf1(a) | (f2bf1(b) << 16);
}

// ---------------- prep: fold BN into per-channel scale/bias ----------------
__global__ void prep_kernel(const float* __restrict__ bk, const float* __restrict__ gamma,
                            const float* __restrict__ beta, const float* __restrict__ rmean,
                            const float* __restrict__ rvar, float* __restrict__ inv_out,
                            float* __restrict__ bc_out) {
    int i = threadIdx.x;  // 256 threads, one per Kc channel
    float inv = gamma[i] * rsqrtf(rvar[i] + 1e-5f);
    inv_out[i] = inv;
    bc_out[i]  = bk[i] * inv + beta[i] - rmean[i] * inv;
}

// ---------------- convert Wk/Ww/Wv fp32 -> bf16 ----------------
__global__ __launch_bounds__(256) void cvt_w_kernel(
    const float* __restrict__ Wk, const float* __restrict__ Ww, const float* __restrict__ Wv,
    u16* __restrict__ Wkbf, u16* __restrict__ Wwbf, u16* __restrict__ Wvbf)
{
    int j = (blockIdx.x * 256 + threadIdx.x) * 4;   // grid 384 -> 393216 elems
    const float* s; u16* d;
    if (j < KC * CIN)          { s = Wk; d = Wkbf; }
    else if (j < 2 * KC * CIN) { j -= KC * CIN;     s = Ww; d = Wwbf; }
    else                       { j -= 2 * KC * CIN; s = Wv; d = Wvbf; }
    float4 v = *(const float4*)&s[j];
    uint2 u;
    u.x = pack2(v.x, v.y);
    u.y = pack2(v.z, v.w);
    *(uint2*)&d[j] = u;
}

// ---------------- transpose+cvt: in [z][C][5184] f32 -> out [z][5184][C] bf16 ----------------
__global__ __launch_bounds__(256) void transpose_cvt_kernel(
    const float* __restrict__ in, u16* __restrict__ out, int C)
{
    const int z  = blockIdx.z;
    const int n0 = blockIdx.x * 32;   // HW
    const int k0 = blockIdx.y * 32;   // C
    __shared__ float t[32][33];
    const int tx = threadIdx.x & 31, ty = threadIdx.x >> 5;   // ty 0..7
    const float* src = in + ((size_t)z * C + k0) * HW + n0;
#pragma unroll
    for (int i = 0; i < 4; i++)
        t[ty + i * 8][tx] = src[(size_t)(ty + i * 8) * HW + tx];
    __syncthreads();
    u16* dst = out + ((size_t)z * HW + n0) * C + k0;
    const int kp  = (threadIdx.x & 15) * 2;
    const int nl0 = threadIdx.x >> 4;           // 0..15
#pragma unroll
    for (int j = 0; j < 2; j++) {
        int nl = nl0 + j * 16;
        u32 u = pack2(t[kp][nl], t[kp + 1][nl]);
        *(u32*)&dst[(size_t)nl * C + kp] = u;
    }
}

// ---------------- bf16 MFMA NT-GEMM, counted-vmcnt 3-buffer pipeline ----------------
// C[z][m][n] = sum_k A[m][k] * B[z][n][k]; optional transposed bf16 out Ct[z][n][m].
__global__ __launch_bounds__(256) void gemm_nt_bf16(
    const u16* __restrict__ A, const u16* __restrict__ B, float* __restrict__ C,
    u16* __restrict__ Ct,
    int M, int N, int K, int nbx, int nby,
    const float* __restrict__ scale, const float* __restrict__ bias, int relu)
{
    // XCD-bijective swizzle (m204 formula), m-fastest decode
    const int tot = nbx * nby * BATCH;
    const int q = tot >> 3, r = tot & 7;
    const int xcd = blockIdx.x & 7;
    const int wg  = (xcd < r ? xcd * (q + 1) : r * (q + 1) + (xcd - r) * q) + (blockIdx.x >> 3);
    const int mb_ = wg % nby;
    const int nb_ = (wg / nby) % nbx;
    const int z   = wg / (nby * nbx);

    const int n0 = nb_ * 128;
    const int m0 = mb_ * 128;
    const size_t boff = (size_t)z * N * K;
    const size_t coff = (size_t)z * M * N;
    const int tid  = threadIdx.x;
    const int wid  = tid >> 6;
    const int lane = tid & 63;

    __shared__ __align__(16) u16 As[3][4][128][8];   // 3 x 8 KB
    __shared__ __align__(16) u16 Bs[3][4][128][8];   // 3 x 8 KB

    const int kg0  = (wid & 1) * 2;
    const int half = (wid >> 1) * 64;

    const u16* gA = A + (size_t)(m0 + half + lane) * K + kg0 * 8;
    int nIdx = n0 + half + lane;
    if (nIdx > N - 1) nIdx = N - 1;               // clamp tail block (dup loads, stores masked)
    const u16* gB = B + boff + (size_t)nIdx * K + kg0 * 8;

    const int wm  = (wid >> 1) * 64;
    const int wn  = (wid & 1) * 64;
    const int l16 = lane & 15;
    const int lq  = lane >> 4;

    f32x4 acc[4][4];
#pragma unroll
    for (int mi = 0; mi < 4; mi++)
#pragma unroll
        for (int ni = 0; ni < 4; ni++)
            acc[mi][ni] = (f32x4){0.f, 0.f, 0.f, 0.f};

#define STAGE(d, kk)                                                                              \
    __builtin_amdgcn_global_load_lds((gp_t)(gA + (kk)),     (lp_t)&As[d][kg0][half][0], 16, 0, 0);\
    __builtin_amdgcn_global_load_lds((gp_t)(gA + (kk) + 8), (lp_t)&As[d][kg0+1][half][0],16, 0, 0);\
    __builtin_amdgcn_global_load_lds((gp_t)(gB + (kk)),     (lp_t)&Bs[d][kg0][half][0], 16, 0, 0);\
    __builtin_amdgcn_global_load_lds((gp_t)(gB + (kk) + 8), (lp_t)&Bs[d][kg0+1][half][0],16, 0, 0);

    const int NT = K >> 5;
    STAGE(0, 0)
    STAGE(1, 32)

    int cur = 0;
    for (int t = 0; t < NT; ++t) {
        if (t + 1 < NT) { asm volatile("s_waitcnt vmcnt(4)" ::: "memory"); }
        else            { asm volatile("s_waitcnt vmcnt(0)" ::: "memory"); }
        __builtin_amdgcn_s_barrier();
        __builtin_amdgcn_sched_barrier(0);

        if (t + 2 < NT) {
            int nb = cur + 2; if (nb >= 3) nb -= 3;
            STAGE(nb, (t + 2) * 32)
        }

        bf16x8 af[4], bf[4];
#pragma unroll
        for (int i = 0; i < 4; i++) {
            af[i] = *(const bf16x8*)&As[cur][lq][wm + i * 16 + l16][0];
            bf[i] = *(const bf16x8*)&Bs[cur][lq][wn + i * 16 + l16][0];
        }
        __builtin_amdgcn_s_setprio(1);
#pragma unroll
        for (int mi = 0; mi < 4; mi++)
#pragma unroll
            for (int ni = 0; ni < 4; ni++)
                acc[mi][ni] = __builtin_amdgcn_mfma_f32_16x16x32_bf16(
                    af[mi], bf[ni], acc[mi][ni], 0, 0, 0);
        __builtin_amdgcn_s_setprio(0);

        cur = (cur == 2) ? 0 : cur + 1;
    }
#undef STAGE

#pragma unroll
    for (int mi = 0; mi < 4; mi++) {
        const int mb = m0 + wm + mi * 16 + lq * 4;
        float sc[4], bi[4];
#pragma unroll
        for (int r2 = 0; r2 < 4; r2++) {
            sc[r2] = scale ? scale[mb + r2] : 1.0f;
            bi[r2] = bias  ? bias[mb + r2]  : 0.0f;
        }
#pragma unroll
        for (int ni = 0; ni < 4; ni++) {
            const int n = n0 + wn + ni * 16 + l16;
            if (n < N) {
                float v[4];
#pragma unroll
                for (int r2 = 0; r2 < 4; r2++) {
                    v[r2] = acc[mi][ni][r2] * sc[r2] + bi[r2];
                    if (relu) v[r2] = fmaxf(v[r2], 0.f);
                    C[coff + (size_t)(mb + r2) * N + n] = v[r2];
                }
                if (Ct) {   // transposed bf16 write: Ct[z][n][m]
                    uint2 u;
                    u.x = pack2(v[0], v[1]);
                    u.y = pack2(v[2], v[3]);
                    *(uint2*)&Ct[(size_t)z * N * M + (size_t)n * M + mb] = u;
                }
            }
        }
    }
}

// ---------------- value MFMA GEMM: valT (SWIZZLED) [b][v][s] bf16 ----------------
__global__ __launch_bounds__(256) void value_mfma_kernel(
    const u16* __restrict__ A, const u16* __restrict__ Bp,
    const float* __restrict__ bv, u16* __restrict__ valT)
{
    const int m0 = blockIdx.x * 128;              // v-block (0 or 128)
    const int b  = blockIdx.y;
    const int tid  = threadIdx.x;
    const int wid  = tid >> 6;
    const int lane = tid & 63;

    __shared__ __align__(16) u16 As[4][128][8];
    __shared__ __align__(16) u16 Bs[4][128][8];

    const int kg0  = (wid & 1) * 2;
    const int half = (wid >> 1) * 64;

    const u16* gA = A + (size_t)(m0 + half + lane) * CIN + kg0 * 8;
    const u16* gB = Bp + (size_t)b * SPV * CIN + (size_t)(half + lane) * CIN + kg0 * 8;

    lp_t lA0 = (lp_t)&As[kg0][half][0];
    lp_t lA1 = (lp_t)&As[kg0 + 1][half][0];
    lp_t lB0 = (lp_t)&Bs[kg0][half][0];
    lp_t lB1 = (lp_t)&Bs[kg0 + 1][half][0];

    const int wm  = (wid >> 1) * 64;
    const int wn  = (wid & 1) * 64;
    const int l16 = lane & 15;
    const int lq  = lane >> 4;

    f32x4 acc[4][4];
#pragma unroll
    for (int mi = 0; mi < 4; mi++)
#pragma unroll
        for (int ni = 0; ni < 4; ni++)
            acc[mi][ni] = (f32x4){0.f, 0.f, 0.f, 0.f};

    for (int k0 = 0; k0 < CIN; k0 += 32) {
        __builtin_amdgcn_global_load_lds((gp_t)(gA + k0),     lA0, 16, 0, 0);
        __builtin_amdgcn_global_load_lds((gp_t)(gA + k0 + 8), lA1, 16, 0, 0);
        __builtin_amdgcn_global_load_lds((gp_t)(gB + k0),     lB0, 16, 0, 0);
        __builtin_amdgcn_global_load_lds((gp_t)(gB + k0 + 8), lB1, 16, 0, 0);
        __syncthreads();

        bf16x8 af[4], bf[4];
#pragma unroll
        for (int i = 0; i < 4; i++) {
            af[i] = *(const bf16x8*)&As[lq][wm + i * 16 + l16][0];
            bf[i] = *(const bf16x8*)&Bs[lq][wn + i * 16 + l16][0];
        }
#pragma unroll
        for (int mi = 0; mi < 4; mi++)
#pragma unroll
            for (int ni = 0; ni < 4; ni++)
                acc[mi][ni] = __builtin_amdgcn_mfma_f32_16x16x32_bf16(
                    af[mi], bf[ni], acc[mi][ni], 0, 0, 0);
        __syncthreads();
    }

    char* vb = (char*)valT + (size_t)b * VC * SPV * 2;
#pragma unroll
    for (int mi = 0; mi < 4; mi++) {
        const int mb = m0 + wm + mi * 16 + lq * 4;
        float bi[4];
#pragma unroll
        for (int r = 0; r < 4; r++) bi[r] = bv[mb + r];
#pragma unroll
        for (int ni = 0; ni < 4; ni++) {
            const int n = wn + ni * 16 + l16;   // s index, 0..127
#pragma unroll
            for (int r = 0; r < 4; r++) {
                const int v = mb + r;
                const int byte = v * 256 + ((n * 2) ^ ((v & 7) << 4));
                *(u16*)(vb + byte) = (u16)f2bf1(acc[mi][ni][r] + bi[r]);
            }
        }
    }
}

// ---------------- PSP pooling px: x [b][512][5184] f32 -> pxb [b][128][512] bf16 ----------------
__global__ __launch_bounds__(128) void psp_pool_px_kernel(
    const float* __restrict__ in, u16* __restrict__ out)
{
    const int c = blockIdx.x;   // 0..511
    const int b = blockIdx.y;
    const int t = threadIdx.x;
    __shared__ float4 row4[1296];
    __shared__ float aux[100];
    float* row = (float*)row4;
    const float* src = in + ((size_t)b * CIN + c) * HW;
    for (int idx = t; idx < 1296; idx += 128)
        row4[idx] = *(const float4*)(src + idx * 4);
    __syncthreads();
    if (t < 64) {
        int r0 = (t >> 3) * 9, c0 = (t & 7) * 9;
        float s = 0.f;
        for (int i = 0; i < 9; i++)
            for (int j = 0; j < 9; j++) s += row[(r0 + i) * WIDTH + c0 + j];
        aux[t] = s;
    } else if (t < 100) {
        int tt = t - 64;
        int r0 = (tt / 6) * 12, c0 = (tt % 6) * 12;
        float s = 0.f;
        for (int i = 0; i < 12; i++)
            for (int j = 0; j < 12; j++) s += row[(r0 + i) * WIDTH + c0 + j];
        aux[64 + tt] = s;
    }
    __syncthreads();
    u16* ob = out + (size_t)b * SPV * CIN + c;
    if (t < 64) ob[(size_t)(46 + t) * CIN] = (u16)f2bf1(aux[t] * (1.f / 81.f));
    if (t < 36) ob[(size_t)(10 + t) * CIN] = (u16)f2bf1(aux[64 + t] * (1.f / 144.f));
    if (t < 9) {
        int r = t / 3, cc = t % 3;
        float s4 = aux[64 + (2 * r) * 6 + 2 * cc] + aux[64 + (2 * r) * 6 + 2 * cc + 1]
                 + aux[64 + (2 * r + 1) * 6 + 2 * cc] + aux[64 + (2 * r + 1) * 6 + 2 * cc + 1];
        ob[(size_t)(1 + t) * CIN] = (u16)f2bf1(s4 * (1.f / 576.f));
    }
    if (t == 0) {
        float s = 0.f;
        for (int i = 0; i < 64; i++) s += aux[i];
        ob[0] = (u16)f2bf1(s * (1.f / 5184.f));
    }
    if (t < 18) ob[(size_t)(110 + t) * CIN] = 0;   // zero pad rows (NaN safety for value GEMM)
}

// ---------------- PSP pooling bf16 (SWIZZLED): k [b][256][5184] -> keyt [b][112][256] ----------------
__global__ __launch_bounds__(128) void psp_pool_bf16_kernel(
    const float* __restrict__ in, u16* __restrict__ out)
{
    const int c = blockIdx.x;   // 0..255
    const int b = blockIdx.y;
    const int t = threadIdx.x;
    __shared__ float4 row4[1296];
    __shared__ float aux[100];
    float* row = (float*)row4;
    const float* src = in + ((size_t)b * KC + c) * HW;
    for (int idx = t; idx < 1296; idx += 128)
        row4[idx] = *(const float4*)(src + idx * 4);
    __syncthreads();
    if (t < 64) {
        int r0 = (t >> 3) * 9, c0 = (t & 7) * 9;
        float s = 0.f;
        for (int i = 0; i < 9; i++)
            for (int j = 0; j < 9; j++) s += row[(r0 + i) * WIDTH + c0 + j];
        aux[t] = s;
    } else if (t < 100) {
        int tt = t - 64;
        int r0 = (tt / 6) * 12, c0 = (tt % 6) * 12;
        float s = 0.f;
        for (int i = 0; i < 12; i++)
            for (int j = 0; j < 12; j++) s += row[(r0 + i) * WIDTH + c0 + j];
        aux[64 + tt] = s;
    }
    __syncthreads();
    char* ob = (char*)out + (size_t)b * NSP * KC * 2;
    const int c2 = c * 2;
#define KWR(S, V) *(u16*)(ob + (S) * 512 + (c2 ^ (((S) & 7) << 4))) = (u16)f2bf1(V)
    if (t < 64) KWR(46 + t, aux[t] * (1.f / 81.f));
    if (t < 36) KWR(10 + t, aux[64 + t] * (1.f / 144.f));
    if (t < 9) {
        int r = t / 3, cc = t % 3;
        float s4 = aux[64 + (2 * r) * 6 + 2 * cc] + aux[64 + (2 * r) * 6 + 2 * cc + 1]
                 + aux[64 + (2 * r + 1) * 6 + 2 * cc] + aux[64 + (2 * r + 1) * 6 + 2 * cc + 1];
        KWR(1 + t, s4 * (1.f / 576.f));
    }
    if (t == 0) {
        float s = 0.f;
        for (int i = 0; i < 64; i++) s += aux[i];
        KWR(0, s * (1.f / 5184.f));
        KWR(110, 0.f);   // zero pad rows
        KWR(111, 0.f);
    }
#undef KWR
}

// ---------------- MFMA attention + FUSED output GEMM ----------------
// 64 px/block, 4 waves. qT [b][5184][256] bf16, keyt [b][112][256] SWZ,
// valT [b][256][128] SWZ, Wwb [512][256] bf16 (k=v contiguous), bw [512].
// out [b][512][5184] fp32 written DIRECTLY (gemm2 fused).
__global__ __launch_bounds__(256) void attn_mfma_kernel(
    const u16* __restrict__ qT, const u16* __restrict__ keyt,
    const u16* __restrict__ valT, const u16* __restrict__ Wwb,
    const float* __restrict__ bw, float* __restrict__ out)
{
    const int b    = blockIdx.y;
    const int tid  = threadIdx.x;
    const int wid  = tid >> 6;
    const int lane = tid & 63;
    const int l16  = lane & 15;
    const int lq   = lane >> 4;
    const int nblk = blockIdx.x * 64;              // block's 64-px base
    const int px0  = nblk + wid * 16;              // wave's 16-px row base (QK/PV phases)

    // LDS map: [0,57344) K swizzled rows 512B -> later P [64][256B] -> later ctx bf16 [64][512B]
    //          [57344,122880) V swizzled rows 256B -> later per-wave 16KB transpose scratch
    __shared__ __align__(16) u16 SM[61440];
    char* base = (char*)SM;
    const int VOFF = 57344;

    // ---- stage K and V (linear copy; global layout already swizzled) ----
    {
        const char* gk = (const char*)keyt + (size_t)b * (NSP * KC * 2);
        const char* gv = (const char*)valT + (size_t)b * (VC * SPV * 2);
#pragma unroll
        for (int i = 0; i < 14; i++) {             // K: 56 KiB
            const int o = (wid * 14 + i) * 1024;
            __builtin_amdgcn_global_load_lds((gp_t)(gk + o + lane * 16), (lp_t)(base + o), 16, 0, 0);
        }
#pragma unroll
        for (int i = 0; i < 16; i++) {             // V: 64 KiB
            const int o = (wid * 16 + i) * 1024;
            __builtin_amdgcn_global_load_lds((gp_t)(gv + o + lane * 16), (lp_t)(base + VOFF + o), 16, 0, 0);
        }
    }

    // ---- preload all 8 q fragments (overlaps with staging drain) ----
    const u16* qrow = qT + ((size_t)b * HW + px0 + l16) * KC + lq * 8;
    bf16x8 aq[8];
#pragma unroll
    for (int ks = 0; ks < 8; ks++) aq[ks] = *(const bf16x8*)(qrow + ks * 32);

    __syncthreads();   // staging complete

    // ==== QK^T from LDS ====
    f32x4 acc[7];
#pragma unroll
    for (int ni = 0; ni < 7; ni++) acc[ni] = (f32x4){0.f, 0.f, 0.f, 0.f};
#pragma unroll
    for (int ks = 0; ks < 8; ks++) {
#pragma unroll
        for (int ni = 0; ni < 7; ni++) {
            const int s = ni * 16 + l16;
            const int byte = s * 512 + ((ks * 64 + lq * 16) ^ ((s & 7) << 4));
            bf16x8 bk = *(const bf16x8*)(base + byte);
            acc[ni] = __builtin_amdgcn_mfma_f32_16x16x32_bf16(aq[ks], bk, acc[ni], 0, 0, 0);
        }
    }
    if (l16 >= 14) acc[6] = (f32x4){-1e30f, -1e30f, -1e30f, -1e30f};  // mask s=110,111

    // ==== softmax (in-register) ====
    float mx[4], sm[4], rn[4];
#pragma unroll
    for (int r = 0; r < 4; r++) {
        float m = acc[0][r];
#pragma unroll
        for (int ni = 1; ni < 7; ni++) m = fmaxf(m, acc[ni][r]);
        m = fmaxf(m, __shfl_xor(m, 1));
        m = fmaxf(m, __shfl_xor(m, 2));
        m = fmaxf(m, __shfl_xor(m, 4));
        m = fmaxf(m, __shfl_xor(m, 8));
        mx[r] = m * 0.0625f;
        sm[r] = 0.f;
    }

    __syncthreads();   // all waves done reading K -> P may overlay

    const int prow = wid * 16 + 4 * lq;
#pragma unroll
    for (int ni = 0; ni < 7; ni++) {
#pragma unroll
        for (int r = 0; r < 4; r++) {
            float p = __expf(acc[ni][r] * 0.0625f - mx[r]);
            sm[r] += p;
            const int row = prow + r;
            const int byte = row * 256 + (((ni * 16 + l16) * 2) ^ ((row & 7) << 4));
            *(u16*)(base + byte) = (u16)f2bf1(p);
        }
    }
    if (l16 < 2) {   // zero pad cols 112..127
#pragma unroll
        for (int r = 0; r < 4; r++) {
            const int row = prow + r;
            const int byte = row * 256 + ((224 + l16 * 16) ^ ((row & 7) << 4));
            *(bf16x8*)(base + byte) = (bf16x8){0, 0, 0, 0, 0, 0, 0, 0};
        }
    }
#pragma unroll
    for (int r = 0; r < 4; r++) {
        float s = sm[r];
        s += __shfl_xor(s, 1);
        s += __shfl_xor(s, 2);
        s += __shfl_xor(s, 4);
        s += __shfl_xor(s, 8);
        rn[r] = 1.f / s;
    }

    __syncthreads();   // P visible (wave-private rows, but cheap + safe)

    // ==== PV from LDS: acc2[ni][r]: row px = wid*16+4lq+r, col v = ni*16+l16 ====
    f32x4 acc2[16];
#pragma unroll
    for (int ni = 0; ni < 16; ni++) acc2[ni] = (f32x4){0.f, 0.f, 0.f, 0.f};
    const int arow = wid * 16 + l16;
    const int aswz = (arow & 7) << 4;
#pragma unroll
    for (int ks = 0; ks < 4; ks++) {
        const int pbyte = arow * 256 + ((ks * 64 + lq * 16) ^ aswz);
        bf16x8 pa = *(const bf16x8*)(base + pbyte);
#pragma unroll
        for (int ni = 0; ni < 16; ni++) {
            const int v = ni * 16 + l16;
            const int vbyte = VOFF + v * 256 + ((ks * 64 + lq * 16) ^ ((v & 7) << 4));
            bf16x8 bvv = *(const bf16x8*)(base + vbyte);
            acc2[ni] = __builtin_amdgcn_mfma_f32_16x16x32_bf16(pa, bvv, acc2[ni], 0, 0, 0);
        }
    }

    __syncthreads();   // all PV done: P and V regions dead

    // ---- write normalized ctx bf16 [64px][256v] (swizzled rows 512B) over P/K region ----
#pragma unroll
    for (int ni = 0; ni < 16; ni++) {
#pragma unroll
        for (int r = 0; r < 4; r++) {
            const int row = prow + r;                       // block-local px
            const int v = ni * 16 + l16;
            const int byte = row * 512 + ((v * 2) ^ ((row & 7) << 4));
            *(u16*)(base + byte) = (u16)f2bf1(acc2[ni][r] * rn[r]);
        }
    }
    __syncthreads();   // ctx visible to all waves

    // ==== fused out-GEMM: out[c][px] = sum_v ctx[px][v] * Ww[c][v]; wave owns 128 c ====
    const int wc0 = wid * 128;
    f32x4 accg[4][8];   // [pi: px-tile][cj: c-tile]
#pragma unroll
    for (int pi = 0; pi < 4; pi++)
#pragma unroll
        for (int cj = 0; cj < 8; cj++)
            accg[pi][cj] = (f32x4){0.f, 0.f, 0.f, 0.f};

    const u16* wwbase = Wwb + (size_t)(wc0 + l16) * VC + lq * 8;
#pragma unroll
    for (int ks = 0; ks < 8; ks++) {
        bf16x8 af[4];
#pragma unroll
        for (int pi = 0; pi < 4; pi++) {
            const int px = pi * 16 + l16;
            const int byte = px * 512 + ((ks * 64 + lq * 16) ^ ((px & 7) << 4));
            af[pi] = *(const bf16x8*)(base + byte);
        }
        bf16x8 bfr[8];
#pragma unroll
        for (int cj = 0; cj < 8; cj++)
            bfr[cj] = *(const bf16x8*)(wwbase + (size_t)cj * 16 * VC + ks * 32);
#pragma unroll
        for (int pi = 0; pi < 4; pi++)
#pragma unroll
            for (int cj = 0; cj < 8; cj++)
                accg[pi][cj] = __builtin_amdgcn_mfma_f32_16x16x32_bf16(
                    af[pi], bfr[cj], accg[pi][cj], 0, 0, 0);
    }

    // ==== epilogue: per-wave LDS transpose (V region scratch) -> coalesced fp32 stores ====
    char* scr = base + VOFF + wid * 16384;   // 16 KB/wave, uses 8 KB
    float* outb = out + (size_t)b * CIN * HW + nblk;
#pragma unroll
    for (int ci = 0; ci < 4; ci++) {         // 32 c per chunk
#pragma unroll
        for (int cjh = 0; cjh < 2; cjh++) {
            const int cj = ci * 2 + cjh;
            const int cl = cjh * 16 + l16;            // 0..31
            const int swz = (cl & 7) << 5;
#pragma unroll
            for (int pi = 0; pi < 4; pi++)
#pragma unroll
                for (int r = 0; r < 4; r++) {
                    const int px = pi * 16 + 4 * lq + r;
                    *(float*)(scr + cl * 256 + ((px * 4) ^ swz)) = accg[pi][cj][r];
                }
        }
        // read rows (4 per instr via lq) + store coalesced; lane l16 -> px l16*4..+3
#pragma unroll
        for (int cr = 0; cr < 8; cr++) {
            const int cl = cr * 4 + lq;
            const int swz = (cl & 7) << 5;
            float4 vv = *(const float4*)(scr + cl * 256 + ((l16 * 16) ^ swz));
            const int c = wc0 + ci * 32 + cl;
            const float bb = bw[c];
            vv.x += bb; vv.y += bb; vv.z += bb; vv.w += bb;
            *(float4*)&outb[(size_t)c * HW + l16 * 4] = vv;
        }
    }
}

extern "C" void kernel_launch(void* const* d_in, const int* in_sizes, int n_in,
                              void* d_out, int out_size, void* d_ws, size_t ws_size,
                              hipStream_t stream)
{
    const float* x     = (const float*)d_in[0];
    const float* Wk    = (const float*)d_in[1];
    const float* bk    = (const float*)d_in[2];
    const float* gamma = (const float*)d_in[3];
    const float* beta  = (const float*)d_in[4];
    const float* rmean = (const float*)d_in[5];
    const float* rvar  = (const float*)d_in[6];
    const float* Wv    = (const float*)d_in[7];
    const float* bv    = (const float*)d_in[8];
    const float* Ww    = (const float*)d_in[9];
    const float* bw    = (const float*)d_in[10];
    float* out = (float*)d_out;

    float* ws    = (float*)d_ws;
    float* k_ws  = ws;                                        // [8][256][5184] f32
    u16*   xT    = (u16*)(k_ws + (size_t)BATCH * KC * HW);    // [8][5184][512] bf16
    u16*   kT    = xT + (size_t)BATCH * HW * CIN;             // [8][5184][256] bf16
    u16*   pxb   = kT + (size_t)BATCH * HW * KC;              // [8][128][512] bf16
    u16*   keytb = pxb + (size_t)BATCH * SPV * CIN;           // [8][112][256] bf16 (swizzled)
    u16*   valT  = keytb + (size_t)BATCH * NSP * KC;          // [8][256][128] bf16 (swizzled)
    u16*   Wkbf  = valT + (size_t)BATCH * VC * SPV;           // [256][512] bf16
    u16*   Wwbf  = Wkbf + (size_t)KC * CIN;                   // [512][256] bf16
    u16*   Wvbf  = Wwbf + (size_t)CIN * VC;                   // [256][512] bf16
    float* inv   = (float*)(Wvbf + (size_t)KC * CIN);         // [256]
    float* bc    = inv + 256;                                 // [256]

    prep_kernel<<<1, 256, 0, stream>>>(bk, gamma, beta, rmean, rvar, inv, bc);
    cvt_w_kernel<<<384, 256, 0, stream>>>(Wk, Ww, Wv, Wkbf, Wwbf, Wvbf);
    psp_pool_px_kernel<<<dim3(CIN, BATCH), 128, 0, stream>>>(x, pxb);
    transpose_cvt_kernel<<<dim3(HW / 32, CIN / 32, BATCH), 256, 0, stream>>>(x, xT, CIN);
    // k = relu(BN(Wk @ x)) : fp32 k_ws (for psp) + bf16 kT (for attn)
    {
        const int nbx = (HW + 127) / 128, nby = KC / 128;
        gemm_nt_bf16<<<nbx * nby * BATCH, 256, 0, stream>>>(
            Wkbf, xT, k_ws, kT, KC, HW, CIN, nbx, nby, inv, bc, 1);
    }
    psp_pool_bf16_kernel<<<dim3(KC, BATCH), 128, 0, stream>>>(k_ws, keytb);
    value_mfma_kernel<<<dim3(2, BATCH), 256, 0, stream>>>(Wvbf, pxb, bv, valT);
    // attention + fused out-GEMM (writes final output directly)
    attn_mfma_kernel<<<dim3(HW / 64, BATCH), 256, 0, stream>>>(
        kT, keytb, valT, Wwbf, bw, out);
}